// Round 1
// baseline (671.071 us; speedup 1.0000x reference)
//
#include <hip/hip_runtime.h>
#include <math.h>

#define XD 128
#define YD 128
#define ZD 96
#define NV (XD*YD*ZD)      /* 1572864 voxels per volume */
#define SXX (YD*ZD)        /* x-stride = 12288 */
#define BIGF 1e10f

// ---------------------------------------------------------------- flags ----
__global__ void k_zero_flags(int* flags) {
    if (threadIdx.x < 8) flags[threadIdx.x] = 0;
}

__global__ void k_flags(const int* __restrict__ gt, int* __restrict__ flags) {
    __shared__ int lf[8];
    if (threadIdx.x < 8) lf[threadIdx.x] = 0;
    __syncthreads();
    const int total = 2 * NV;
    for (int i = blockIdx.x * blockDim.x + threadIdx.x; i < total;
         i += gridDim.x * blockDim.x) {
        int g = gt[i];
        int b = (i >= NV) ? 1 : 0;
        int slot = b * 4 + g;
        if (lf[slot] == 0) atomicOr(&lf[slot], 1);
    }
    __syncthreads();
    if (threadIdx.x < 8 && lf[threadIdx.x]) atomicOr(&flags[threadIdx.x], 1);
}

// ----------------------------------------------------- pass X (with init) ----
// lines along x; line id lq = y*ZD + z  (12288 per volume)
__global__ __launch_bounds__(256) void k_pass_x_init(const int* __restrict__ gt,
                                                     float* __restrict__ out,
                                                     int pair0) {
    const int lv   = blockIdx.y;
    const int pair = pair0 + (lv >> 1);
    const int s    = lv & 1;                // 0: posdis (mask=onehot), 1: negdis
    const int b    = pair / 3;
    const int ci   = pair % 3 + 1;
    const int l    = threadIdx.x & 63;
    const int w    = threadIdx.x >> 6;
    const int lq   = blockIdx.x * 64 + l;

    __shared__ float tile[64 * 129];
    const int* gp = gt + (size_t)b * NV + lq;
    for (int j = w; j < XD; j += 4) {
        int g = gp[(size_t)j * SXX];
        // f = BIG where (gt==ci) for s=0, where (gt!=ci) for s=1
        tile[l * 129 + j] = ((((g == ci) ? 1 : 0) != s)) ? BIGF : 0.0f;
    }
    __syncthreads();

    float m[32], d[32];
#pragma unroll
    for (int k = 0; k < 32; ++k) { m[k] = 3.4e38f; d[k] = (float)(w + 4 * k); }
    const float* tl = tile + l * 129;
    for (int j = 0; j < XD; ++j) {
        float fj = tl[j];
#pragma unroll
        for (int k = 0; k < 32; ++k) {
            m[k] = fminf(m[k], fmaf(d[k], d[k], fj));
            d[k] -= 1.0f;
        }
    }
    float* op = out + (size_t)lv * NV + lq;
#pragma unroll
    for (int k = 0; k < 32; ++k) op[(size_t)(w + 4 * k) * SXX] = m[k];
}

// ------------------------------------------------------------- pass Y ----
// lines along y; line id lq = x*ZD + z (12288 per volume)
__global__ __launch_bounds__(256) void k_pass_y(const float* __restrict__ in,
                                                float* __restrict__ out) {
    const int lv = blockIdx.y;
    const int l  = threadIdx.x & 63;
    const int w  = threadIdx.x >> 6;
    const int lq = blockIdx.x * 64 + l;
    const int x  = lq / ZD;
    const int z  = lq - x * ZD;
    const size_t base = (size_t)lv * NV + (size_t)x * SXX + z;

    __shared__ float tile[64 * 129];
    for (int j = w; j < YD; j += 4) tile[l * 129 + j] = in[base + (size_t)j * ZD];
    __syncthreads();

    float m[32], d[32];
#pragma unroll
    for (int k = 0; k < 32; ++k) { m[k] = 3.4e38f; d[k] = (float)(w + 4 * k); }
    const float* tl = tile + l * 129;
    for (int j = 0; j < YD; ++j) {
        float fj = tl[j];
#pragma unroll
        for (int k = 0; k < 32; ++k) {
            m[k] = fminf(m[k], fmaf(d[k], d[k], fj));
            d[k] -= 1.0f;
        }
    }
#pragma unroll
    for (int k = 0; k < 32; ++k) out[base + (size_t)(w + 4 * k) * ZD] = m[k];
}

// ------------------------------------------------------------- pass Z ----
// lines along z (contiguous); line id lq = x*YD + y (16384 per volume)
__global__ __launch_bounds__(256) void k_pass_z(const float* __restrict__ in,
                                                float* __restrict__ out) {
    const int lv = blockIdx.y;
    const int l  = threadIdx.x & 63;
    const int w  = threadIdx.x >> 6;
    const int q0 = blockIdx.x * 64;

    __shared__ float tile[64 * 97];
    const size_t sb = (size_t)lv * NV + (size_t)q0 * ZD;
    for (int o = threadIdx.x; o < 64 * ZD; o += 256) {
        int line = o / ZD, j = o - line * ZD;
        tile[line * 97 + j] = in[sb + o];
    }
    __syncthreads();

    float m[24], d[24];
#pragma unroll
    for (int k = 0; k < 24; ++k) { m[k] = 3.4e38f; d[k] = (float)(w + 4 * k); }
    const float* tl = tile + l * 97;
    for (int j = 0; j < ZD; ++j) {
        float fj = tl[j];
#pragma unroll
        for (int k = 0; k < 24; ++k) {
            m[k] = fminf(m[k], fmaf(d[k], d[k], fj));
            d[k] -= 1.0f;
        }
    }
    __syncthreads();               // everyone done reading tile
    float* tw = tile + l * 97;
#pragma unroll
    for (int k = 0; k < 24; ++k) tw[w + 4 * k] = m[k];
    __syncthreads();
    for (int o = threadIdx.x; o < 64 * ZD; o += 256) {
        int line = o / ZD, j = o - line * ZD;
        out[sb + o] = tile[line * 97 + j];
    }
}

// -------------------------------------------------------------- accum ----
__global__ __launch_bounds__(256) void k_accum(const float* __restrict__ pos2,
                                               const float* __restrict__ neg2,
                                               const int* __restrict__ gt,
                                               const float* __restrict__ net,
                                               const int* __restrict__ flags,
                                               double* __restrict__ partials,
                                               int b, int ci) {
    double ls = 0.0;
    const int* g = gt + (size_t)b * NV;
    const float* nb = net + (size_t)b * 4 * NV;
    const int anyp = flags[b * 4 + ci];
    for (int idx = blockIdx.x * 256 + threadIdx.x; idx < NV; idx += 2048 * 256) {
        float v0 = nb[idx];
        float v1 = nb[NV + idx];
        float v2 = nb[2 * NV + idx];
        float v3 = nb[3 * NV + idx];
        float mx = fmaxf(fmaxf(v0, v1), fmaxf(v2, v3));
        float e0 = expf(v0 - mx), e1 = expf(v1 - mx);
        float e2 = expf(v2 - mx), e3 = expf(v3 - mx);
        float esum = e0 + e1 + e2 + e3;
        float ec = (ci == 1) ? e1 : ((ci == 2) ? e2 : e3);
        float prob = ec / esum;

        float phi = 0.0f;
        if (anyp) {
            int g0 = g[idx];
            bool bnd = false;
            if (g0 == ci) {
                int z = idx % ZD;
                int t = idx / ZD;
                int y = t % YD;
                int x = t / YD;
                if (x > 0      && g[idx - SXX] != ci) bnd = true;
                if (x < XD - 1 && g[idx + SXX] != ci) bnd = true;
                if (y > 0      && g[idx - ZD]  != ci) bnd = true;
                if (y < YD - 1 && g[idx + ZD]  != ci) bnd = true;
                if (z > 0      && g[idx - 1]   != ci) bnd = true;
                if (z < ZD - 1 && g[idx + 1]   != ci) bnd = true;
            }
            if (!bnd) phi = sqrtf(neg2[idx]) - sqrtf(pos2[idx]);
        }
        ls += (double)(prob * phi);
    }
    __shared__ double sd[256];
    sd[threadIdx.x] = ls;
    __syncthreads();
    for (int off = 128; off > 0; off >>= 1) {
        if (threadIdx.x < off) sd[threadIdx.x] += sd[threadIdx.x + off];
        __syncthreads();
    }
    if (threadIdx.x == 0) partials[blockIdx.x] = sd[0];
}

// -------------------------------------------------------------- reduce ----
__global__ void k_reduce(const double* __restrict__ partials, int n,
                         float* __restrict__ out) {
    __shared__ double sd[256];
    double ls = 0.0;
    for (int i = threadIdx.x; i < n; i += 256) ls += partials[i];
    sd[threadIdx.x] = ls;
    __syncthreads();
    for (int off = 128; off > 0; off >>= 1) {
        if (threadIdx.x < off) sd[threadIdx.x] += sd[threadIdx.x + off];
        __syncthreads();
    }
    if (threadIdx.x == 0) out[0] = (float)(sd[0] / 9437184.0);
}

// ---------------------------------------------------------------- launch ----
extern "C" void kernel_launch(void* const* d_in, const int* in_sizes, int n_in,
                              void* d_out, int out_size, void* d_ws, size_t ws_size,
                              hipStream_t stream) {
    const float* net = (const float*)d_in[0];
    const int*   gt  = (const int*)d_in[1];
    float* out = (float*)d_out;
    char* ws = (char*)d_ws;

    const size_t perPairBuf = (size_t)2 * NV * sizeof(float);  // pos+neg volume
    const size_t tail = (size_t)6 * 2048 * sizeof(double) + 64;

    int G = 1;
    if (ws_size >= 12 * perPairBuf + tail)      G = 6;
    else if (ws_size >= 6 * perPairBuf + tail)  G = 3;

    float*  A        = (float*)ws;
    float*  Bbuf     = (float*)(ws + (size_t)G * perPairBuf);
    double* partials = (double*)(ws + (size_t)2 * G * perPairBuf);
    int*    flags    = (int*)(ws + (size_t)2 * G * perPairBuf +
                              (size_t)6 * 2048 * sizeof(double));

    hipLaunchKernelGGL(k_zero_flags, dim3(1), dim3(64), 0, stream, flags);
    hipLaunchKernelGGL(k_flags, dim3(512), dim3(256), 0, stream, gt, flags);

    for (int pair0 = 0; pair0 < 6; pair0 += G) {
        int gcnt = (6 - pair0 < G) ? (6 - pair0) : G;
        hipLaunchKernelGGL(k_pass_x_init, dim3(SXX / 64, 2 * gcnt), dim3(256), 0,
                           stream, gt, A, pair0);
        hipLaunchKernelGGL(k_pass_y, dim3(12288 / 64, 2 * gcnt), dim3(256), 0,
                           stream, A, Bbuf);
        hipLaunchKernelGGL(k_pass_z, dim3((XD * YD) / 64, 2 * gcnt), dim3(256), 0,
                           stream, Bbuf, A);
        for (int p = pair0; p < pair0 + gcnt; ++p) {
            int lv0 = (p - pair0) * 2;
            hipLaunchKernelGGL(k_accum, dim3(2048), dim3(256), 0, stream,
                               A + (size_t)lv0 * NV, A + (size_t)(lv0 + 1) * NV,
                               gt, net, flags, partials + (size_t)p * 2048,
                               p / 3, p % 3 + 1);
        }
    }
    hipLaunchKernelGGL(k_reduce, dim3(1), dim3(256), 0, stream, partials,
                       6 * 2048, out);
}

// Round 3
// 226.163 us; speedup vs baseline: 2.9672x; 2.9672x over previous
//
#include <hip/hip_runtime.h>
#include <math.h>

#define XD 128
#define YD 128
#define ZD 96
#define NV (XD*YD*ZD)      /* 1572864 voxels per volume */
#define SXX (YD*ZD)        /* x-stride = 12288 */
#define BIGF 1e10f

// ---------------------------------------------------------------- flags ----
__global__ void k_zero_flags(int* flags) {
    if (threadIdx.x < 8) flags[threadIdx.x] = 0;
}

__global__ void k_flags(const int* __restrict__ gt, int* __restrict__ flags) {
    __shared__ int lf[8];
    if (threadIdx.x < 8) lf[threadIdx.x] = 0;
    __syncthreads();
    const int total = 2 * NV;
    for (int i = blockIdx.x * blockDim.x + threadIdx.x; i < total;
         i += gridDim.x * blockDim.x) {
        int g = gt[i];
        int b = (i >= NV) ? 1 : 0;
        int slot = b * 4 + g;
        if (lf[slot] == 0) atomicOr(&lf[slot], 1);
    }
    __syncthreads();
    if (threadIdx.x < 8 && lf[threadIdx.x]) atomicOr(&flags[threadIdx.x], 1);
}

// -------------------------------------------- pass X: binary run-length scan
// Binary input {0,BIG} => EDT along x = (dist to nearest source)^2 via
// forward+backward run-length scans (exact; values are small ints in fp32).
// Block: 64 lines (lq = y*ZD+z). blockIdx.y = batch offset bb.
// Waves 0..2 scan class cls0+w for all 64 lines; wave 3 idles during scan.
// dtile slots are LOCAL (2*c+s in [0,6)); output slot = bb*2*ncl + 2*c + s.
__global__ __launch_bounds__(256) void k_scan_x(const int* __restrict__ gt,
                                                float* __restrict__ out,
                                                int batch0, int cls0, int ncl) {
    const int bb  = blockIdx.y;
    const int myb = batch0 + bb;
    const int l   = threadIdx.x & 63;
    const int w   = threadIdx.x >> 6;
    const int lq  = blockIdx.x * 64 + l;

    __shared__ unsigned char gtile[64 * 132];
    __shared__ unsigned char dtile[6 * 64 * 132];

    const int* gp = gt + (size_t)myb * NV + lq;
    for (int j = w; j < XD; j += 4)
        gtile[l * 132 + j] = (unsigned char)gp[(size_t)j * SXX];
    __syncthreads();

    if (w < ncl) {                       // wave w owns class cls0+w
        const int ci = cls0 + w;
        const unsigned char* gl = gtile + l * 132;
        unsigned char* dN = dtile + (2 * w + 0) * (64 * 132) + l * 132;
        unsigned char* dI = dtile + (2 * w + 1) * (64 * 132) + l * 132;
        int fN = 200, fI = 200;
        for (int j = 0; j < XD; ++j) {
            int g = gl[j];
            fN = (g != ci) ? 0 : ((fN < 200) ? fN + 1 : 200);
            fI = (g == ci) ? 0 : ((fI < 200) ? fI + 1 : 200);
            dN[j] = (unsigned char)fN;
            dI[j] = (unsigned char)fI;
        }
        int bN = 200, bI = 200;
        for (int j = XD - 1; j >= 0; --j) {
            int g = gl[j];
            bN = (g != ci) ? 0 : ((bN < 200) ? bN + 1 : 200);
            bI = (g == ci) ? 0 : ((bI < 200) ? bI + 1 : 200);
            if (bN < dN[j]) dN[j] = (unsigned char)bN;
            if (bI < dI[j]) dI[j] = (unsigned char)bI;
        }
    }
    __syncthreads();

    for (int c = 0; c < ncl; ++c) {
        for (int s = 0; s < 2; ++s) {
            const unsigned char* dt = dtile + (2 * c + s) * (64 * 132) + l * 132;
            float* op = out + (size_t)(bb * 2 * ncl + 2 * c + s) * NV + lq;
            for (int j = w; j < XD; j += 4) {
                int d = dt[j];
                op[(size_t)j * SXX] = (d > 127) ? BIGF : (float)(d * d);
            }
        }
    }
}

// -------------------------------------------- pass Y: windowed brute force --
// argmin j* for output i satisfies (i-j*)^2 <= f[i]; W = floor(sqrt(max f over
// the wave's outputs)) bounds the search. Excluded candidates are >= the min,
// so the result is bit-identical to the full brute force.
__global__ __launch_bounds__(512) void k_pass_y_w(const float* __restrict__ in,
                                                  float* __restrict__ out) {
    const int lv = blockIdx.y;
    const int l  = threadIdx.x & 63;
    const int wv = threadIdx.x >> 6;        // 0..7 (constant within a wave)
    const int lq = blockIdx.x * 64 + l;
    const int x  = lq / ZD;
    const int z  = lq - x * ZD;
    const size_t base = (size_t)lv * NV + (size_t)x * SXX + z;

    __shared__ float tile[64 * 129];
    for (int j = wv; j < YD; j += 8)
        tile[l * 129 + j] = in[base + (size_t)j * ZD];
    __syncthreads();

    const float* tl = tile + l * 129;
    const int i0 = wv * 16;
    float m[16];
    float mx = 0.0f;
#pragma unroll
    for (int k = 0; k < 16; ++k) { m[k] = tl[i0 + k]; mx = fmaxf(mx, m[k]); }
#pragma unroll
    for (int off = 1; off < 64; off <<= 1) mx = fmaxf(mx, __shfl_xor(mx, off));
    int W = (int)sqrtf(mx);
    if (W > 127) W = 127;
    const int jlo = (i0 - W > 0) ? (i0 - W) : 0;
    const int jhi = (i0 + 15 + W < 127) ? (i0 + 15 + W) : 127;

    float d[16];
#pragma unroll
    for (int k = 0; k < 16; ++k) d[k] = (float)(i0 + k - jlo);
    for (int j = jlo; j <= jhi; ++j) {
        float fj = tl[j];
#pragma unroll
        for (int k = 0; k < 16; ++k) {
            m[k] = fminf(m[k], fmaf(d[k], d[k], fj));
            d[k] -= 1.0f;
        }
    }
#pragma unroll
    for (int k = 0; k < 16; ++k) out[base + (size_t)(i0 + k) * ZD] = m[k];
}

// -------------------------------------------- pass Z: windowed brute force --
__global__ __launch_bounds__(384) void k_pass_z_w(const float* __restrict__ in,
                                                  float* __restrict__ out) {
    const int lv = blockIdx.y;
    const int l  = threadIdx.x & 63;
    const int wv = threadIdx.x >> 6;        // 0..5
    const size_t sb = (size_t)lv * NV + (size_t)blockIdx.x * 64 * ZD;

    __shared__ float tile[64 * 97];
    for (int o = threadIdx.x; o < 64 * ZD; o += 384) {
        int line = o / ZD, j = o - line * ZD;
        tile[line * 97 + j] = in[sb + o];
    }
    __syncthreads();

    const float* tl = tile + l * 97;
    const int i0 = wv * 16;
    float m[16];
    float mx = 0.0f;
#pragma unroll
    for (int k = 0; k < 16; ++k) { m[k] = tl[i0 + k]; mx = fmaxf(mx, m[k]); }
#pragma unroll
    for (int off = 1; off < 64; off <<= 1) mx = fmaxf(mx, __shfl_xor(mx, off));
    int W = (int)sqrtf(mx);
    if (W > 95) W = 95;
    const int jlo = (i0 - W > 0) ? (i0 - W) : 0;
    const int jhi = (i0 + 15 + W < 95) ? (i0 + 15 + W) : 95;

    float d[16];
#pragma unroll
    for (int k = 0; k < 16; ++k) d[k] = (float)(i0 + k - jlo);
    for (int j = jlo; j <= jhi; ++j) {
        float fj = tl[j];
#pragma unroll
        for (int k = 0; k < 16; ++k) {
            m[k] = fminf(m[k], fmaf(d[k], d[k], fj));
            d[k] -= 1.0f;
        }
    }
    __syncthreads();               // all reads of tile done
#pragma unroll
    for (int k = 0; k < 16; ++k) tile[l * 97 + i0 + k] = m[k];
    __syncthreads();
    for (int o = threadIdx.x; o < 64 * ZD; o += 384) {
        int line = o / ZD, j = o - line * ZD;
        out[sb + o] = tile[line * 97 + j];
    }
}

// ---------------------------------------- accum: fused per batch (3 classes)
__global__ __launch_bounds__(256) void k_accum_batch(const float* __restrict__ vols,
                                                     const int* __restrict__ gt,
                                                     const float* __restrict__ net,
                                                     const int* __restrict__ flags,
                                                     double* __restrict__ partials,
                                                     int b) {
    double ls = 0.0;
    const int* g = gt + (size_t)b * NV;
    const float* nb = net + (size_t)b * 4 * NV;
    const int fl1 = flags[b * 4 + 1], fl2 = flags[b * 4 + 2], fl3 = flags[b * 4 + 3];
    for (int idx = blockIdx.x * 256 + threadIdx.x; idx < NV; idx += 1024 * 256) {
        float v0 = nb[idx];
        float v1 = nb[NV + idx];
        float v2 = nb[2 * NV + idx];
        float v3 = nb[3 * NV + idx];
        float mxv = fmaxf(fmaxf(v0, v1), fmaxf(v2, v3));
        float e0 = expf(v0 - mxv), e1 = expf(v1 - mxv);
        float e2 = expf(v2 - mxv), e3 = expf(v3 - mxv);
        float esum = e0 + e1 + e2 + e3;

        int g0 = g[idx];
        int z = idx % ZD;
        int t = idx / ZD;
        int y = t % YD;
        int x = t / YD;
        int a0 = (x > 0)      ? g[idx - SXX] : g0;
        int a1 = (x < XD - 1) ? g[idx + SXX] : g0;
        int b0 = (y > 0)      ? g[idx - ZD]  : g0;
        int b1 = (y < YD - 1) ? g[idx + ZD]  : g0;
        int c0 = (z > 0)      ? g[idx - 1]   : g0;
        int c1 = (z < ZD - 1) ? g[idx + 1]   : g0;

#pragma unroll
        for (int ci = 1; ci <= 3; ++ci) {
            int flg = (ci == 1) ? fl1 : ((ci == 2) ? fl2 : fl3);
            float ec = (ci == 1) ? e1 : ((ci == 2) ? e2 : e3);
            float phi = 0.0f;
            if (flg) {
                bool bnd = (g0 == ci) && (a0 != ci || a1 != ci || b0 != ci ||
                                          b1 != ci || c0 != ci || c1 != ci);
                if (!bnd)
                    phi = sqrtf(vols[(size_t)(2 * ci - 1) * NV + idx]) -
                          sqrtf(vols[(size_t)(2 * ci - 2) * NV + idx]);
            }
            ls += (double)((ec / esum) * phi);
        }
    }
    __shared__ double sd[256];
    sd[threadIdx.x] = ls;
    __syncthreads();
    for (int off = 128; off > 0; off >>= 1) {
        if (threadIdx.x < off) sd[threadIdx.x] += sd[threadIdx.x + off];
        __syncthreads();
    }
    if (threadIdx.x == 0) partials[blockIdx.x] = sd[0];
}

// -------------------------------------------- accum: per-pair (G=1 fallback)
__global__ __launch_bounds__(256) void k_accum(const float* __restrict__ pos2,
                                               const float* __restrict__ neg2,
                                               const int* __restrict__ gt,
                                               const float* __restrict__ net,
                                               const int* __restrict__ flags,
                                               double* __restrict__ partials,
                                               int b, int ci) {
    double ls = 0.0;
    const int* g = gt + (size_t)b * NV;
    const float* nb = net + (size_t)b * 4 * NV;
    const int anyp = flags[b * 4 + ci];
    for (int idx = blockIdx.x * 256 + threadIdx.x; idx < NV; idx += 2048 * 256) {
        float v0 = nb[idx];
        float v1 = nb[NV + idx];
        float v2 = nb[2 * NV + idx];
        float v3 = nb[3 * NV + idx];
        float mx = fmaxf(fmaxf(v0, v1), fmaxf(v2, v3));
        float e0 = expf(v0 - mx), e1 = expf(v1 - mx);
        float e2 = expf(v2 - mx), e3 = expf(v3 - mx);
        float esum = e0 + e1 + e2 + e3;
        float ec = (ci == 1) ? e1 : ((ci == 2) ? e2 : e3);
        float prob = ec / esum;

        float phi = 0.0f;
        if (anyp) {
            int g0 = g[idx];
            bool bnd = false;
            if (g0 == ci) {
                int z = idx % ZD;
                int t = idx / ZD;
                int y = t % YD;
                int x = t / YD;
                if (x > 0      && g[idx - SXX] != ci) bnd = true;
                if (x < XD - 1 && g[idx + SXX] != ci) bnd = true;
                if (y > 0      && g[idx - ZD]  != ci) bnd = true;
                if (y < YD - 1 && g[idx + ZD]  != ci) bnd = true;
                if (z > 0      && g[idx - 1]   != ci) bnd = true;
                if (z < ZD - 1 && g[idx + 1]   != ci) bnd = true;
            }
            if (!bnd) phi = sqrtf(neg2[idx]) - sqrtf(pos2[idx]);
        }
        ls += (double)(prob * phi);
    }
    __shared__ double sd[256];
    sd[threadIdx.x] = ls;
    __syncthreads();
    for (int off = 128; off > 0; off >>= 1) {
        if (threadIdx.x < off) sd[threadIdx.x] += sd[threadIdx.x + off];
        __syncthreads();
    }
    if (threadIdx.x == 0) partials[blockIdx.x] = sd[0];
}

// -------------------------------------------------------------- reduce ----
__global__ void k_reduce(const double* __restrict__ partials, int n,
                         float* __restrict__ out) {
    __shared__ double sd[256];
    double ls = 0.0;
    for (int i = threadIdx.x; i < n; i += 256) ls += partials[i];
    sd[threadIdx.x] = ls;
    __syncthreads();
    for (int off = 128; off > 0; off >>= 1) {
        if (threadIdx.x < off) sd[threadIdx.x] += sd[threadIdx.x + off];
        __syncthreads();
    }
    if (threadIdx.x == 0) out[0] = (float)(sd[0] / 9437184.0);
}

// ---------------------------------------------------------------- launch ----
extern "C" void kernel_launch(void* const* d_in, const int* in_sizes, int n_in,
                              void* d_out, int out_size, void* d_ws, size_t ws_size,
                              hipStream_t stream) {
    const float* net = (const float*)d_in[0];
    const int*   gt  = (const int*)d_in[1];
    float* out = (float*)d_out;
    char* ws = (char*)d_ws;

    const size_t perPairBuf = (size_t)2 * NV * sizeof(float);  // pos+neg volume
    const size_t tail = (size_t)6 * 2048 * sizeof(double) + 64;

    int G = 1;
    if (ws_size >= 12 * perPairBuf + tail)      G = 6;
    else if (ws_size >= 6 * perPairBuf + tail)  G = 3;

    float*  A        = (float*)ws;
    float*  Bbuf     = (float*)(ws + (size_t)G * perPairBuf);
    double* partials = (double*)(ws + (size_t)2 * G * perPairBuf);
    int*    flags    = (int*)(ws + (size_t)2 * G * perPairBuf +
                              (size_t)6 * 2048 * sizeof(double));

    hipLaunchKernelGGL(k_zero_flags, dim3(1), dim3(64), 0, stream, flags);
    hipLaunchKernelGGL(k_flags, dim3(512), dim3(256), 0, stream, gt, flags);

    if (G >= 3) {
        for (int pair0 = 0; pair0 < 6; pair0 += G) {
            int gcnt = (6 - pair0 < G) ? (6 - pair0) : G;
            int nb = (gcnt == 6) ? 2 : 1;
            hipLaunchKernelGGL(k_scan_x, dim3(SXX / 64, nb), dim3(256), 0,
                               stream, gt, A, pair0 / 3, 1, 3);
            hipLaunchKernelGGL(k_pass_y_w, dim3(12288 / 64, 2 * gcnt), dim3(512),
                               0, stream, A, Bbuf);
            hipLaunchKernelGGL(k_pass_z_w, dim3((XD * YD) / 64, 2 * gcnt),
                               dim3(384), 0, stream, Bbuf, A);
            for (int bb = 0; bb < nb; ++bb) {
                int b = (gcnt == 6) ? bb : (pair0 / 3);
                hipLaunchKernelGGL(k_accum_batch, dim3(1024), dim3(256), 0,
                                   stream, A + (size_t)bb * 6 * NV, gt, net,
                                   flags, partials + (size_t)b * 1024, b);
            }
        }
        hipLaunchKernelGGL(k_reduce, dim3(1), dim3(256), 0, stream, partials,
                           2048, out);
    } else {
        for (int p = 0; p < 6; ++p) {
            hipLaunchKernelGGL(k_scan_x, dim3(SXX / 64, 1), dim3(256), 0,
                               stream, gt, A, p / 3, p % 3 + 1, 1);
            hipLaunchKernelGGL(k_pass_y_w, dim3(12288 / 64, 2), dim3(512), 0,
                               stream, A, Bbuf);
            hipLaunchKernelGGL(k_pass_z_w, dim3((XD * YD) / 64, 2), dim3(384),
                               0, stream, Bbuf, A);
            hipLaunchKernelGGL(k_accum, dim3(2048), dim3(256), 0, stream,
                               A, A + (size_t)NV, gt, net, flags,
                               partials + (size_t)p * 2048, p / 3, p % 3 + 1);
        }
        hipLaunchKernelGGL(k_reduce, dim3(1), dim3(256), 0, stream, partials,
                           6 * 2048, out);
    }
}

// Round 4
// 130.510 us; speedup vs baseline: 5.1419x; 1.7329x over previous
//
#include <hip/hip_runtime.h>
#include <math.h>

#define XD 128
#define YD 128
#define ZD 96
#define NV (XD*YD*ZD)      /* 1572864 voxels per volume */
#define SXX (YD*ZD)        /* x-stride = 12288 */
#define BIGF 1e10f
#define SENT 49152         /* u16 sentinel: > any real d^2 (max 41283) */

// ---------------------------------------------------------------- flags ----
__global__ void k_zero_flags(int* flags) {
    if (threadIdx.x < 8) flags[threadIdx.x] = 0;
}

__global__ void k_flags(const int* __restrict__ gt, int* __restrict__ flags) {
    __shared__ int lf[8];
    if (threadIdx.x < 8) lf[threadIdx.x] = 0;
    __syncthreads();
    const int total = 2 * NV;
    for (int i = blockIdx.x * blockDim.x + threadIdx.x; i < total;
         i += gridDim.x * blockDim.x) {
        int g = gt[i];
        int b = (i >= NV) ? 1 : 0;
        int slot = b * 4 + g;
        if (lf[slot] == 0) atomicOr(&lf[slot], 1);
    }
    __syncthreads();
    if (threadIdx.x < 8 && lf[threadIdx.x]) atomicOr(&flags[threadIdx.x], 1);
}

// -------------------------------------------- pass X: binary run-length scan
// Emits u16 d^2 (SENT where no source in line). blockIdx.y = batch offset bb;
// actual batch = batch0+bb. Output slot = bb*6 + 2*c + s.
__global__ __launch_bounds__(256) void k_scan_x(const int* __restrict__ gt,
                                                unsigned short* __restrict__ out,
                                                int batch0) {
    const int bb  = blockIdx.y;
    const int myb = batch0 + bb;
    const int l   = threadIdx.x & 63;
    const int w   = threadIdx.x >> 6;
    const int lq  = blockIdx.x * 64 + l;

    __shared__ unsigned char gtile[64 * 132];
    __shared__ unsigned char dtile[6 * 64 * 132];

    const int* gp = gt + (size_t)myb * NV + lq;
    for (int j = w; j < XD; j += 4)
        gtile[l * 132 + j] = (unsigned char)gp[(size_t)j * SXX];
    __syncthreads();

    if (w < 3) {                         // wave w owns class w+1
        const int ci = w + 1;
        const unsigned char* gl = gtile + l * 132;
        unsigned char* dN = dtile + (2 * w + 0) * (64 * 132) + l * 132;
        unsigned char* dI = dtile + (2 * w + 1) * (64 * 132) + l * 132;
        int fN = 200, fI = 200;
        for (int j = 0; j < XD; ++j) {
            int g = gl[j];
            fN = (g != ci) ? 0 : ((fN < 200) ? fN + 1 : 200);
            fI = (g == ci) ? 0 : ((fI < 200) ? fI + 1 : 200);
            dN[j] = (unsigned char)fN;
            dI[j] = (unsigned char)fI;
        }
        int bN = 200, bI = 200;
        for (int j = XD - 1; j >= 0; --j) {
            int g = gl[j];
            bN = (g != ci) ? 0 : ((bN < 200) ? bN + 1 : 200);
            bI = (g == ci) ? 0 : ((bI < 200) ? bI + 1 : 200);
            if (bN < dN[j]) dN[j] = (unsigned char)bN;
            if (bI < dI[j]) dI[j] = (unsigned char)bI;
        }
    }
    __syncthreads();

    for (int c = 0; c < 3; ++c) {
        for (int s = 0; s < 2; ++s) {
            const unsigned char* dt = dtile + (2 * c + s) * (64 * 132) + l * 132;
            unsigned short* op = out + (size_t)(bb * 6 + 2 * c + s) * NV + lq;
            for (int j = w; j < XD; j += 4) {
                int d = dt[j];
                op[(size_t)j * SXX] =
                    (d > 127) ? (unsigned short)SENT : (unsigned short)(d * d);
            }
        }
    }
}

// ---------------- pass Y: center-outward scan with provable early exit -----
// Candidates j = i +/- t for t = 0,1,2,...; stop once for all wave outputs
// m <= t^2 (future candidates are tl[j] + t'^2 > m, strictly). Exact.
// Sentinel inputs (SENT=49152) participate as plain floats: a real candidate
// (<= 16129 + t^2 <= 32258) always beats a sentinel one (>= 49152).
__global__ __launch_bounds__(512) void k_pass_y(const unsigned short* __restrict__ in,
                                                unsigned short* __restrict__ out) {
    const int lv = blockIdx.y;
    const int l  = threadIdx.x & 63;
    const int wv = threadIdx.x >> 6;        // 0..7
    const int lq = blockIdx.x * 64 + l;
    const int x  = lq / ZD;
    const int z  = lq - x * ZD;
    const size_t base = (size_t)lv * NV + (size_t)x * SXX + z;

    __shared__ float tile[64 * 145];        // 8 pad | 128 data | 9 pad; 145%32=17
    float* row = tile + l * 145;
    for (int p = wv; p < 17; p += 8) row[(p < 8) ? p : (128 + p)] = BIGF;
    for (int j = wv; j < YD; j += 8) row[8 + j] = (float)in[base + (size_t)j * ZD];
    __syncthreads();

    const int i0 = wv * 16;
    const float* tl = row + 8 + i0;
    float m[16];
#pragma unroll
    for (int k = 0; k < 16; ++k) m[k] = tl[k];

    int t = 1;
    bool done = false;
#pragma unroll
    for (int chunk = 0; chunk < 2; ++chunk) {
        if (!done) {
#pragma unroll
            for (int u = 0; u < 4; ++u, ++t) {
                float t2 = (float)(t * t);
#pragma unroll
                for (int k = 0; k < 16; ++k)
                    m[k] = fminf(m[k], fminf(tl[k - t], tl[k + t]) + t2);
            }
            float mm = m[0];
#pragma unroll
            for (int k = 1; k < 16; ++k) mm = fmaxf(mm, m[k]);
            done = __all(mm <= (float)((t - 1) * (t - 1))) != 0;
        }
    }
    while (!done && t < 128) {              // rare slow path, clamped reads
        for (int u = 0; u < 4; ++u, ++t) {
            float t2 = (float)(t * t);
#pragma unroll
            for (int k = 0; k < 16; ++k) {
                int jm = i0 + k - t; if (jm < -8) jm = -8;
                int jp = i0 + k + t; if (jp > 135) jp = 135;
                m[k] = fminf(m[k], fminf(row[8 + jm], row[8 + jp]) + t2);
            }
        }
        float mm = m[0];
#pragma unroll
        for (int k = 1; k < 16; ++k) mm = fmaxf(mm, m[k]);
        done = __all(mm <= (float)((t - 1) * (t - 1))) != 0;
    }

#pragma unroll
    for (int k = 0; k < 16; ++k) {
        float v = m[k];
        out[base + (size_t)(i0 + k) * ZD] =
            (v >= (float)SENT) ? (unsigned short)SENT : (unsigned short)v;
    }
}

// ---------------- pass Z: same centered scheme, contiguous lines -----------
__global__ __launch_bounds__(384) void k_pass_z(const unsigned short* __restrict__ in,
                                                unsigned short* __restrict__ out) {
    const int lv = blockIdx.y;
    const int l  = threadIdx.x & 63;
    const int wv = threadIdx.x >> 6;        // 0..5
    const size_t sb = (size_t)lv * NV + (size_t)blockIdx.x * 64 * ZD;

    __shared__ float tile[64 * 113];        // 8 pad | 96 data | 9 pad; 113%32=17
    float* row = tile + l * 113;
    for (int p = wv; p < 17; p += 6) row[(p < 8) ? p : (96 + p)] = BIGF;
    for (int o = threadIdx.x; o < 64 * ZD; o += 384) {
        int line = o / ZD, j = o - line * ZD;
        tile[line * 113 + 8 + j] = (float)in[sb + o];
    }
    __syncthreads();

    const int i0 = wv * 16;
    const float* tl = row + 8 + i0;
    float m[16];
#pragma unroll
    for (int k = 0; k < 16; ++k) m[k] = tl[k];

    int t = 1;
    bool done = false;
#pragma unroll
    for (int chunk = 0; chunk < 2; ++chunk) {
        if (!done) {
#pragma unroll
            for (int u = 0; u < 4; ++u, ++t) {
                float t2 = (float)(t * t);
#pragma unroll
                for (int k = 0; k < 16; ++k)
                    m[k] = fminf(m[k], fminf(tl[k - t], tl[k + t]) + t2);
            }
            float mm = m[0];
#pragma unroll
            for (int k = 1; k < 16; ++k) mm = fmaxf(mm, m[k]);
            done = __all(mm <= (float)((t - 1) * (t - 1))) != 0;
        }
    }
    while (!done && t < 96) {
        for (int u = 0; u < 4; ++u, ++t) {
            float t2 = (float)(t * t);
#pragma unroll
            for (int k = 0; k < 16; ++k) {
                int jm = i0 + k - t; if (jm < -8) jm = -8;
                int jp = i0 + k + t; if (jp > 103) jp = 103;
                m[k] = fminf(m[k], fminf(row[8 + jm], row[8 + jp]) + t2);
            }
        }
        float mm = m[0];
#pragma unroll
        for (int k = 1; k < 16; ++k) mm = fmaxf(mm, m[k]);
        done = __all(mm <= (float)((t - 1) * (t - 1))) != 0;
    }

    __syncthreads();                        // all reads of tile done
#pragma unroll
    for (int k = 0; k < 16; ++k) row[8 + i0 + k] = m[k];
    __syncthreads();
    for (int o = threadIdx.x; o < 64 * ZD; o += 384) {
        int line = o / ZD, j = o - line * ZD;
        float v = tile[line * 113 + 8 + j];
        out[sb + o] = (v >= (float)SENT) ? (unsigned short)SENT : (unsigned short)v;
    }
}

// ---------------- accum: fused per batch, both batches in one grid ---------
__global__ __launch_bounds__(256) void k_accum_batch(const unsigned short* __restrict__ vols,
                                                     const int* __restrict__ gt,
                                                     const float* __restrict__ net,
                                                     const int* __restrict__ flags,
                                                     double* __restrict__ partials,
                                                     int batch0) {
    const int b = batch0 + blockIdx.y;
    double ls = 0.0;
    const int* g = gt + (size_t)b * NV;
    const float* nb = net + (size_t)b * 4 * NV;
    const unsigned short* vb = vols + (size_t)blockIdx.y * 6 * NV;
    const int fl1 = flags[b * 4 + 1], fl2 = flags[b * 4 + 2], fl3 = flags[b * 4 + 3];
    for (int idx = blockIdx.x * 256 + threadIdx.x; idx < NV; idx += 1024 * 256) {
        float v0 = nb[idx];
        float v1 = nb[NV + idx];
        float v2 = nb[2 * NV + idx];
        float v3 = nb[3 * NV + idx];
        float mxv = fmaxf(fmaxf(v0, v1), fmaxf(v2, v3));
        float e0 = expf(v0 - mxv), e1 = expf(v1 - mxv);
        float e2 = expf(v2 - mxv), e3 = expf(v3 - mxv);
        float esum = e0 + e1 + e2 + e3;

        int g0 = g[idx];
        int z = idx % ZD;
        int t = idx / ZD;
        int y = t % YD;
        int x = t / YD;
        int a0 = (x > 0)      ? g[idx - SXX] : g0;
        int a1 = (x < XD - 1) ? g[idx + SXX] : g0;
        int b0 = (y > 0)      ? g[idx - ZD]  : g0;
        int b1 = (y < YD - 1) ? g[idx + ZD]  : g0;
        int c0 = (z > 0)      ? g[idx - 1]   : g0;
        int c1 = (z < ZD - 1) ? g[idx + 1]   : g0;

#pragma unroll
        for (int ci = 1; ci <= 3; ++ci) {
            int flg = (ci == 1) ? fl1 : ((ci == 2) ? fl2 : fl3);
            float ec = (ci == 1) ? e1 : ((ci == 2) ? e2 : e3);
            float phi = 0.0f;
            if (flg) {
                bool bnd = (g0 == ci) && (a0 != ci || a1 != ci || b0 != ci ||
                                          b1 != ci || c0 != ci || c1 != ci);
                if (!bnd)
                    phi = sqrtf((float)vb[(size_t)(2 * ci - 1) * NV + idx]) -
                          sqrtf((float)vb[(size_t)(2 * ci - 2) * NV + idx]);
            }
            ls += (double)((ec / esum) * phi);
        }
    }
    __shared__ double sd[256];
    sd[threadIdx.x] = ls;
    __syncthreads();
    for (int off = 128; off > 0; off >>= 1) {
        if (threadIdx.x < off) sd[threadIdx.x] += sd[threadIdx.x + off];
        __syncthreads();
    }
    if (threadIdx.x == 0) partials[(size_t)b * 1024 + blockIdx.x] = sd[0];
}

// -------------------------------------------------------------- reduce ----
__global__ void k_reduce(const double* __restrict__ partials, int n,
                         float* __restrict__ out) {
    __shared__ double sd[256];
    double ls = 0.0;
    for (int i = threadIdx.x; i < n; i += 256) ls += partials[i];
    sd[threadIdx.x] = ls;
    __syncthreads();
    for (int off = 128; off > 0; off >>= 1) {
        if (threadIdx.x < off) sd[threadIdx.x] += sd[threadIdx.x + off];
        __syncthreads();
    }
    if (threadIdx.x == 0) out[0] = (float)(sd[0] / 9437184.0);
}

// ---------------------------------------------------------------- launch ----
extern "C" void kernel_launch(void* const* d_in, const int* in_sizes, int n_in,
                              void* d_out, int out_size, void* d_ws, size_t ws_size,
                              hipStream_t stream) {
    const float* net = (const float*)d_in[0];
    const int*   gt  = (const int*)d_in[1];
    float* out = (float*)d_out;
    char* ws = (char*)d_ws;

    const size_t volsB1 = (size_t)6 * NV * sizeof(unsigned short);  // 18.9 MB
    const size_t tail   = (size_t)2048 * sizeof(double) + 64;

    // nb=2: both batches per pipeline stage (needs 75.5 MB; round-1 evidence
    // shows ws >= 151 MB). nb=1 fallback processes batches sequentially.
    const int nb = (ws_size >= 4 * volsB1 + tail) ? 2 : 1;

    unsigned short* xbuf = (unsigned short*)ws;
    unsigned short* ybuf = (unsigned short*)(ws + (size_t)nb * 2 * volsB1);
    double* partials = (double*)(ws + (size_t)nb * 2 * 2 * volsB1);
    int* flags = (int*)((char*)partials + 2048 * sizeof(double));

    hipLaunchKernelGGL(k_zero_flags, dim3(1), dim3(64), 0, stream, flags);
    hipLaunchKernelGGL(k_flags, dim3(512), dim3(256), 0, stream, gt, flags);

    for (int b0 = 0; b0 < 2; b0 += nb) {
        hipLaunchKernelGGL(k_scan_x, dim3(SXX / 64, nb), dim3(256), 0, stream,
                           gt, xbuf, b0);
        hipLaunchKernelGGL(k_pass_y, dim3(12288 / 64, 6 * nb), dim3(512), 0,
                           stream, xbuf, ybuf);
        hipLaunchKernelGGL(k_pass_z, dim3((XD * YD) / 64, 6 * nb), dim3(384), 0,
                           stream, ybuf, xbuf);
        hipLaunchKernelGGL(k_accum_batch, dim3(1024, nb), dim3(256), 0, stream,
                           xbuf, gt, net, flags, partials, b0);
    }
    hipLaunchKernelGGL(k_reduce, dim3(1), dim3(256), 0, stream, partials,
                       2048, out);
}

// Round 5
// 116.699 us; speedup vs baseline: 5.7504x; 1.1183x over previous
//
#include <hip/hip_runtime.h>
#include <math.h>

#define XD 128
#define YD 128
#define ZD 96
#define NV (XD*YD*ZD)      /* 1572864 voxels per volume */
#define SXX (YD*ZD)        /* x-stride = 12288 */
#define BIGF 1e10f
#define SENT 49152         /* u16 sentinel: > any real d^2 (max 41283) */

// ---------------------------------------------------------------- flags ----
__global__ void k_zero_flags(int* flags) {
    if (threadIdx.x < 8) flags[threadIdx.x] = 0;
}

// -------------------------------------------- pass X: binary run-length scan
// Emits u16 d^2 (SENT where no source in line). Also accumulates per-batch
// class-presence bitmask into flags[batch] (replaces the old k_flags pass).
__global__ __launch_bounds__(256) void k_scan_x(const int* __restrict__ gt,
                                                unsigned short* __restrict__ out,
                                                int* __restrict__ flags,
                                                int batch0) {
    const int bb  = blockIdx.y;
    const int myb = batch0 + bb;
    const int l   = threadIdx.x & 63;
    const int w   = threadIdx.x >> 6;
    const int lq  = blockIdx.x * 64 + l;

    __shared__ unsigned char gtile[64 * 132];
    __shared__ unsigned char dtile[6 * 64 * 132];
    __shared__ int blkbits;
    if (threadIdx.x == 0) blkbits = 0;

    int mybits = 0;
    const int* gp = gt + (size_t)myb * NV + lq;
    for (int j = w; j < XD; j += 4) {
        int g = gp[(size_t)j * SXX];
        mybits |= 1 << g;
        gtile[l * 132 + j] = (unsigned char)g;
    }
#pragma unroll
    for (int off = 32; off; off >>= 1) mybits |= __shfl_xor(mybits, off);
    __syncthreads();
    if ((threadIdx.x & 63) == 0) atomicOr(&blkbits, mybits);

    if (w < 3) {                         // wave w owns class w+1
        const int ci = w + 1;
        const unsigned char* gl = gtile + l * 132;
        unsigned char* dN = dtile + (2 * w + 0) * (64 * 132) + l * 132;
        unsigned char* dI = dtile + (2 * w + 1) * (64 * 132) + l * 132;
        int fN = 200, fI = 200;
        for (int j = 0; j < XD; ++j) {
            int g = gl[j];
            fN = (g != ci) ? 0 : ((fN < 200) ? fN + 1 : 200);
            fI = (g == ci) ? 0 : ((fI < 200) ? fI + 1 : 200);
            dN[j] = (unsigned char)fN;
            dI[j] = (unsigned char)fI;
        }
        int bN = 200, bI = 200;
        for (int j = XD - 1; j >= 0; --j) {
            int g = gl[j];
            bN = (g != ci) ? 0 : ((bN < 200) ? bN + 1 : 200);
            bI = (g == ci) ? 0 : ((bI < 200) ? bI + 1 : 200);
            if (bN < dN[j]) dN[j] = (unsigned char)bN;
            if (bI < dI[j]) dI[j] = (unsigned char)bI;
        }
    }
    __syncthreads();
    if (threadIdx.x == 0) atomicOr(&flags[myb], blkbits);

    for (int c = 0; c < 3; ++c) {
        for (int s = 0; s < 2; ++s) {
            const unsigned char* dt = dtile + (2 * c + s) * (64 * 132) + l * 132;
            unsigned short* op = out + (size_t)(bb * 6 + 2 * c + s) * NV + lq;
            for (int j = w; j < XD; j += 4) {
                int d = dt[j];
                op[(size_t)j * SXX] =
                    (d > 127) ? (unsigned short)SENT : (unsigned short)(d * d);
            }
        }
    }
}

// ---------------- pass Y: center-outward, register-windowed t<=8 -----------
// Candidates j = i +/- t; stop when all wave outputs have m <= t^2 (future
// candidates strictly greater). For t<=8 all indices are static after unroll:
// 32-float register window r[] = row[i0-8 .. i0+23]. Bit-exact vs brute force.
__global__ __launch_bounds__(512) void k_pass_y(const unsigned short* __restrict__ in,
                                                unsigned short* __restrict__ out) {
    const int lv = blockIdx.y;
    const int l  = threadIdx.x & 63;
    const int wv = threadIdx.x >> 6;        // 0..7
    const int lq = blockIdx.x * 64 + l;
    const int x  = lq / ZD;
    const int z  = lq - x * ZD;
    const size_t base = (size_t)lv * NV + (size_t)x * SXX + z;

    __shared__ float tile[64 * 145];        // 8 pad | 128 data | 9 pad
    float* row = tile + l * 145;
    for (int p = wv; p < 17; p += 8) row[(p < 8) ? p : (128 + p)] = BIGF;
    for (int j = wv; j < YD; j += 8) row[8 + j] = (float)in[base + (size_t)j * ZD];
    __syncthreads();

    const int i0 = wv * 16;
    float r[32];
#pragma unroll
    for (int q = 0; q < 32; ++q) r[q] = row[i0 + q];   // tile[l*145 + i0 + q]

    float m[16];
#pragma unroll
    for (int k = 0; k < 16; ++k) m[k] = r[k + 8];

#pragma unroll
    for (int t = 1; t <= 4; ++t) {
        const float t2 = (float)(t * t);
#pragma unroll
        for (int k = 0; k < 16; ++k)
            m[k] = fminf(m[k], fminf(r[k + 8 - t], r[k + 8 + t]) + t2);
    }
    float mm = m[0];
#pragma unroll
    for (int k = 1; k < 16; ++k) mm = fmaxf(mm, m[k]);
    bool done = __all(mm <= 16.0f) != 0;

    if (!done) {
#pragma unroll
        for (int t = 5; t <= 8; ++t) {
            const float t2 = (float)(t * t);
#pragma unroll
            for (int k = 0; k < 16; ++k)
                m[k] = fminf(m[k], fminf(r[k + 8 - t], r[k + 8 + t]) + t2);
        }
        mm = m[0];
#pragma unroll
        for (int k = 1; k < 16; ++k) mm = fmaxf(mm, m[k]);
        done = __all(mm <= 64.0f) != 0;
    }

    int t = 9;
    while (!done && t < 128) {              // rare slow path, clamped LDS reads
        for (int u = 0; u < 4; ++u, ++t) {
            float t2 = (float)(t * t);
#pragma unroll
            for (int k = 0; k < 16; ++k) {
                int jm = i0 + k - t; if (jm < -8) jm = -8;
                int jp = i0 + k + t; if (jp > 135) jp = 135;
                m[k] = fminf(m[k], fminf(row[8 + jm], row[8 + jp]) + t2);
            }
        }
        mm = m[0];
#pragma unroll
        for (int k = 1; k < 16; ++k) mm = fmaxf(mm, m[k]);
        done = __all(mm <= (float)((t - 1) * (t - 1))) != 0;
    }

#pragma unroll
    for (int k = 0; k < 16; ++k) {
        float v = m[k];
        out[base + (size_t)(i0 + k) * ZD] =
            (v >= (float)SENT) ? (unsigned short)SENT : (unsigned short)v;
    }
}

// ---------------- pass Z: same scheme, contiguous lines, ushort2 I/O -------
__global__ __launch_bounds__(384) void k_pass_z(const unsigned short* __restrict__ in,
                                                unsigned short* __restrict__ out) {
    const int lv = blockIdx.y;
    const int l  = threadIdx.x & 63;
    const int wv = threadIdx.x >> 6;        // 0..5
    const size_t sb = (size_t)lv * NV + (size_t)blockIdx.x * 64 * ZD;

    __shared__ float tile[64 * 113];        // 8 pad | 96 data | 9 pad
    float* row = tile + l * 113;
    for (int p = wv; p < 17; p += 6) row[(p < 8) ? p : (96 + p)] = BIGF;
    {
        const unsigned int* in2 = (const unsigned int*)(in + sb);
        for (int o = threadIdx.x; o < (64 * ZD) / 2; o += 384) {
            unsigned int v = in2[o];
            int e = o * 2;
            int line = e / ZD, j = e - line * ZD;
            tile[line * 113 + 8 + j]     = (float)(v & 0xFFFF);
            tile[line * 113 + 8 + j + 1] = (float)(v >> 16);
        }
    }
    __syncthreads();

    const int i0 = wv * 16;
    float r[32];
#pragma unroll
    for (int q = 0; q < 32; ++q) r[q] = row[i0 + q];

    float m[16];
#pragma unroll
    for (int k = 0; k < 16; ++k) m[k] = r[k + 8];

#pragma unroll
    for (int t = 1; t <= 4; ++t) {
        const float t2 = (float)(t * t);
#pragma unroll
        for (int k = 0; k < 16; ++k)
            m[k] = fminf(m[k], fminf(r[k + 8 - t], r[k + 8 + t]) + t2);
    }
    float mm = m[0];
#pragma unroll
    for (int k = 1; k < 16; ++k) mm = fmaxf(mm, m[k]);
    bool done = __all(mm <= 16.0f) != 0;

    if (!done) {
#pragma unroll
        for (int t = 5; t <= 8; ++t) {
            const float t2 = (float)(t * t);
#pragma unroll
            for (int k = 0; k < 16; ++k)
                m[k] = fminf(m[k], fminf(r[k + 8 - t], r[k + 8 + t]) + t2);
        }
        mm = m[0];
#pragma unroll
        for (int k = 1; k < 16; ++k) mm = fmaxf(mm, m[k]);
        done = __all(mm <= 64.0f) != 0;
    }

    int t = 9;
    while (!done && t < 96) {
        for (int u = 0; u < 4; ++u, ++t) {
            float t2 = (float)(t * t);
#pragma unroll
            for (int k = 0; k < 16; ++k) {
                int jm = i0 + k - t; if (jm < -8) jm = -8;
                int jp = i0 + k + t; if (jp > 103) jp = 103;
                m[k] = fminf(m[k], fminf(row[8 + jm], row[8 + jp]) + t2);
            }
        }
        mm = m[0];
#pragma unroll
        for (int k = 1; k < 16; ++k) mm = fmaxf(mm, m[k]);
        done = __all(mm <= (float)((t - 1) * (t - 1))) != 0;
    }

    __syncthreads();                        // all reads of tile done
#pragma unroll
    for (int k = 0; k < 16; ++k) row[8 + i0 + k] = m[k];
    __syncthreads();
    {
        unsigned int* out2 = (unsigned int*)(out + sb);
        for (int o = threadIdx.x; o < (64 * ZD) / 2; o += 384) {
            int e = o * 2;
            int line = e / ZD, j = e - line * ZD;
            float v0 = tile[line * 113 + 8 + j];
            float v1 = tile[line * 113 + 8 + j + 1];
            unsigned int u0 = (v0 >= (float)SENT) ? SENT : (unsigned int)v0;
            unsigned int u1 = (v1 >= (float)SENT) ? SENT : (unsigned int)v1;
            out2[o] = u0 | (u1 << 16);
        }
    }
}

// ---------------- accum: fused per batch, both batches in one grid ---------
__global__ __launch_bounds__(256) void k_accum_batch(const unsigned short* __restrict__ vols,
                                                     const int* __restrict__ gt,
                                                     const float* __restrict__ net,
                                                     const int* __restrict__ flags,
                                                     double* __restrict__ partials,
                                                     int batch0) {
    const int b = batch0 + blockIdx.y;
    double ls = 0.0;
    const int* g = gt + (size_t)b * NV;
    const float* nb = net + (size_t)b * 4 * NV;
    const unsigned short* vb = vols + (size_t)blockIdx.y * 6 * NV;
    const int fbits = flags[b];
    for (int idx = blockIdx.x * 256 + threadIdx.x; idx < NV; idx += 1024 * 256) {
        float v0 = nb[idx];
        float v1 = nb[NV + idx];
        float v2 = nb[2 * NV + idx];
        float v3 = nb[3 * NV + idx];
        float mxv = fmaxf(fmaxf(v0, v1), fmaxf(v2, v3));
        float e0 = __expf(v0 - mxv), e1 = __expf(v1 - mxv);
        float e2 = __expf(v2 - mxv), e3 = __expf(v3 - mxv);
        float esum = e0 + e1 + e2 + e3;

        int g0 = g[idx];
        int z = idx % ZD;
        int t = idx / ZD;
        int y = t % YD;
        int x = t / YD;
        int a0 = (x > 0)      ? g[idx - SXX] : g0;
        int a1 = (x < XD - 1) ? g[idx + SXX] : g0;
        int b0 = (y > 0)      ? g[idx - ZD]  : g0;
        int b1 = (y < YD - 1) ? g[idx + ZD]  : g0;
        int c0 = (z > 0)      ? g[idx - 1]   : g0;
        int c1 = (z < ZD - 1) ? g[idx + 1]   : g0;

#pragma unroll
        for (int ci = 1; ci <= 3; ++ci) {
            int flg = (fbits >> ci) & 1;
            float ec = (ci == 1) ? e1 : ((ci == 2) ? e2 : e3);
            float phi = 0.0f;
            if (flg) {
                bool bnd = (g0 == ci) && (a0 != ci || a1 != ci || b0 != ci ||
                                          b1 != ci || c0 != ci || c1 != ci);
                if (!bnd)
                    phi = sqrtf((float)vb[(size_t)(2 * ci - 1) * NV + idx]) -
                          sqrtf((float)vb[(size_t)(2 * ci - 2) * NV + idx]);
            }
            ls += (double)((ec / esum) * phi);
        }
    }
    __shared__ double sd[256];
    sd[threadIdx.x] = ls;
    __syncthreads();
    for (int off = 128; off > 0; off >>= 1) {
        if (threadIdx.x < off) sd[threadIdx.x] += sd[threadIdx.x + off];
        __syncthreads();
    }
    if (threadIdx.x == 0) partials[(size_t)b * 1024 + blockIdx.x] = sd[0];
}

// -------------------------------------------------------------- reduce ----
__global__ void k_reduce(const double* __restrict__ partials, int n,
                         float* __restrict__ out) {
    __shared__ double sd[256];
    double ls = 0.0;
    for (int i = threadIdx.x; i < n; i += 256) ls += partials[i];
    sd[threadIdx.x] = ls;
    __syncthreads();
    for (int off = 128; off > 0; off >>= 1) {
        if (threadIdx.x < off) sd[threadIdx.x] += sd[threadIdx.x + off];
        __syncthreads();
    }
    if (threadIdx.x == 0) out[0] = (float)(sd[0] / 9437184.0);
}

// ---------------------------------------------------------------- launch ----
extern "C" void kernel_launch(void* const* d_in, const int* in_sizes, int n_in,
                              void* d_out, int out_size, void* d_ws, size_t ws_size,
                              hipStream_t stream) {
    const float* net = (const float*)d_in[0];
    const int*   gt  = (const int*)d_in[1];
    float* out = (float*)d_out;
    char* ws = (char*)d_ws;

    const size_t volsB1 = (size_t)6 * NV * sizeof(unsigned short);  // 18.9 MB
    const size_t tail   = (size_t)2048 * sizeof(double) + 64;

    const int nb = (ws_size >= 4 * volsB1 + tail) ? 2 : 1;

    unsigned short* xbuf = (unsigned short*)ws;
    unsigned short* ybuf = (unsigned short*)(ws + (size_t)nb * 2 * volsB1);
    double* partials = (double*)(ws + (size_t)nb * 2 * 2 * volsB1);
    int* flags = (int*)((char*)partials + 2048 * sizeof(double));

    hipLaunchKernelGGL(k_zero_flags, dim3(1), dim3(64), 0, stream, flags);

    for (int b0 = 0; b0 < 2; b0 += nb) {
        hipLaunchKernelGGL(k_scan_x, dim3(SXX / 64, nb), dim3(256), 0, stream,
                           gt, xbuf, flags, b0);
        hipLaunchKernelGGL(k_pass_y, dim3(12288 / 64, 6 * nb), dim3(512), 0,
                           stream, xbuf, ybuf);
        hipLaunchKernelGGL(k_pass_z, dim3((XD * YD) / 64, 6 * nb), dim3(384), 0,
                           stream, ybuf, xbuf);
        hipLaunchKernelGGL(k_accum_batch, dim3(1024, nb), dim3(256), 0, stream,
                           xbuf, gt, net, flags, partials, b0);
    }
    hipLaunchKernelGGL(k_reduce, dim3(1), dim3(256), 0, stream, partials,
                       2048, out);
}

// Round 6
// 114.727 us; speedup vs baseline: 5.8493x; 1.0172x over previous
//
#include <hip/hip_runtime.h>
#include <math.h>

#define XD 128
#define YD 128
#define ZD 96
#define NV (XD*YD*ZD)      /* 1572864 voxels per volume */
#define SXX (YD*ZD)        /* x-stride = 12288 */
#define BIGF 1e10f
#define SENT 49152         /* sentinel: > any real d^2 (max 41283) */
#define TSTR 145           /* tile row stride: 8 pad | 128 | 9 pad; %32=17 */

// ---------------------------------------------------------------- flags ----
__global__ void k_zero_flags(int* flags) {
    if (threadIdx.x < 8) flags[threadIdx.x] = 0;
}

// -------------------------------------------- pass X: binary run-length scan
// Emits u8 distance d (d>127 => no source in line). Also accumulates the
// per-batch class-presence bitmask into flags[batch].
__global__ __launch_bounds__(256) void k_scan_x(const int* __restrict__ gt,
                                                unsigned char* __restrict__ out,
                                                int* __restrict__ flags,
                                                int batch0) {
    const int bb  = blockIdx.y;
    const int myb = batch0 + bb;
    const int l   = threadIdx.x & 63;
    const int w   = threadIdx.x >> 6;
    const int lq  = blockIdx.x * 64 + l;

    __shared__ unsigned char gtile[64 * 132];
    __shared__ unsigned char dtile[6 * 64 * 132];
    __shared__ int blkbits;
    if (threadIdx.x == 0) blkbits = 0;

    int mybits = 0;
    const int* gp = gt + (size_t)myb * NV + lq;
    for (int j = w; j < XD; j += 4) {
        int g = gp[(size_t)j * SXX];
        mybits |= 1 << g;
        gtile[l * 132 + j] = (unsigned char)g;
    }
#pragma unroll
    for (int off = 32; off; off >>= 1) mybits |= __shfl_xor(mybits, off);
    __syncthreads();
    if ((threadIdx.x & 63) == 0) atomicOr(&blkbits, mybits);

    if (w < 3) {                         // wave w owns class w+1
        const int ci = w + 1;
        const unsigned char* gl = gtile + l * 132;
        unsigned char* dN = dtile + (2 * w + 0) * (64 * 132) + l * 132;
        unsigned char* dI = dtile + (2 * w + 1) * (64 * 132) + l * 132;
        int fN = 200, fI = 200;
        for (int j = 0; j < XD; ++j) {
            int g = gl[j];
            fN = (g != ci) ? 0 : ((fN < 200) ? fN + 1 : 200);
            fI = (g == ci) ? 0 : ((fI < 200) ? fI + 1 : 200);
            dN[j] = (unsigned char)fN;
            dI[j] = (unsigned char)fI;
        }
        int bN = 200, bI = 200;
        for (int j = XD - 1; j >= 0; --j) {
            int g = gl[j];
            bN = (g != ci) ? 0 : ((bN < 200) ? bN + 1 : 200);
            bI = (g == ci) ? 0 : ((bI < 200) ? bI + 1 : 200);
            if (bN < dN[j]) dN[j] = (unsigned char)bN;
            if (bI < dI[j]) dI[j] = (unsigned char)bI;
        }
    }
    __syncthreads();
    if (threadIdx.x == 0) atomicOr(&flags[myb], blkbits);

    for (int c = 0; c < 3; ++c) {
        for (int s = 0; s < 2; ++s) {
            const unsigned char* dt = dtile + (2 * c + s) * (64 * 132) + l * 132;
            unsigned char* op = out + (size_t)(bb * 6 + 2 * c + s) * NV + lq;
            for (int j = w; j < XD; j += 4) op[(size_t)j * SXX] = dt[j];
        }
    }
}

// ------------- one 16-output EDT chunk, center-outward, early exit ---------
// row0 points at the j=0 element of a line in LDS; valid j in [-8, L+7]
// (BIGF pads). Bit-exact vs brute-force min (excluded candidates strictly
// greater; t^2 exact small ints in f32).
template<int STRIDE, int L>
__device__ __forceinline__ void edt_chunk(const float* __restrict__ row0,
                                          int i0, float m[16]) {
    const float* tl = row0 + (i0 - 8) * STRIDE;
    float r[32];
#pragma unroll
    for (int q = 0; q < 32; ++q) r[q] = tl[q * STRIDE];
#pragma unroll
    for (int k = 0; k < 16; ++k) m[k] = r[k + 8];

#pragma unroll
    for (int t = 1; t <= 4; ++t) {
        const float t2 = (float)(t * t);
#pragma unroll
        for (int k = 0; k < 16; ++k)
            m[k] = fminf(m[k], fminf(r[k + 8 - t], r[k + 8 + t]) + t2);
    }
    float mm = m[0];
#pragma unroll
    for (int k = 1; k < 16; ++k) mm = fmaxf(mm, m[k]);
    bool done = __all(mm <= 16.0f) != 0;

    if (!done) {
#pragma unroll
        for (int t = 5; t <= 8; ++t) {
            const float t2 = (float)(t * t);
#pragma unroll
            for (int k = 0; k < 16; ++k)
                m[k] = fminf(m[k], fminf(r[k + 8 - t], r[k + 8 + t]) + t2);
        }
        mm = m[0];
#pragma unroll
        for (int k = 1; k < 16; ++k) mm = fmaxf(mm, m[k]);
        done = __all(mm <= 64.0f) != 0;
    }

    int t = 9;
    while (!done && t < L) {             // rare slow path, clamped LDS reads
        for (int u = 0; u < 4; ++u, ++t) {
            float t2 = (float)(t * t);
#pragma unroll
            for (int k = 0; k < 16; ++k) {
                int jm = i0 + k - t; if (jm < -8) jm = -8;
                int jp = i0 + k + t; if (jp > L + 7) jp = L + 7;
                m[k] = fminf(m[k], fminf(row0[jm * STRIDE], row0[jp * STRIDE]) + t2);
            }
        }
        mm = m[0];
#pragma unroll
        for (int k = 1; k < 16; ++k) mm = fmaxf(mm, m[k]);
        done = __all(mm <= (float)((t - 1) * (t - 1))) != 0;
    }
}

// ------------- fused Y+Z pass: one x-plane resident in LDS -----------------
// Tile [112][145]: rows = 8 pad | 96 z | 8 pad, cols = 8 pad | 128 y | 9 pad.
// Phase Y: 768 chunks c = i0_idx*96 + z (lanes share i0, z consecutive ->
// bank stride 17, conflict-free). Phase Z: c = zc*128 + y (lanes consecutive
// y -> consecutive banks). Each thread does exactly 2 chunks per phase.
__global__ __launch_bounds__(384, 3) void k_pass_yz(const unsigned char* __restrict__ in,
                                                    unsigned short* __restrict__ out) {
    const int lv  = blockIdx.y;          // volume slot
    const int x   = blockIdx.x;
    const int tid = threadIdx.x;
    __shared__ float tile[112 * TSTR];

    for (int i = tid; i < 16 * TSTR; i += 384) {          // z-pad rows
        int r = i / TSTR, c = i - r * TSTR;
        int row = (r < 8) ? r : 96 + r;
        tile[row * TSTR + c] = BIGF;
    }
    for (int i = tid; i < 96 * 17; i += 384) {            // y-pad cols
        int r = i / 17, c = i - r * 17;
        int col = (c < 8) ? c : 128 + c;
        tile[(8 + r) * TSTR + col] = BIGF;
    }
    const unsigned int* ip =
        (const unsigned int*)(in + (size_t)lv * NV + (size_t)x * SXX);
    for (int o = tid; o < SXX / 4; o += 384) {            // u8 d -> f32 d^2
        unsigned int v = ip[o];
        int e = o * 4;
        int y = e / ZD, z = e - y * ZD;
        float* dst = &tile[(8 + z) * TSTR + 8 + y];
#pragma unroll
        for (int q = 0; q < 4; ++q) {
            unsigned int d = (v >> (8 * q)) & 0xFF;
            dst[q * TSTR] = (d > 127) ? (float)SENT : (float)(d * d);
        }
    }
    __syncthreads();

    float mA[16], mB[16];
    {   // ---- phase Y ----
        const int zA = tid % 96, iA = (tid / 96) * 16;
        const int cB = tid + 384;
        const int zB = cB % 96, iB = (cB / 96) * 16;
        edt_chunk<1, YD>(&tile[(8 + zA) * TSTR + 8], iA, mA);
        edt_chunk<1, YD>(&tile[(8 + zB) * TSTR + 8], iB, mB);
        __syncthreads();
#pragma unroll
        for (int k = 0; k < 16; ++k) {
            float v = mA[k];
            tile[(8 + zA) * TSTR + 8 + iA + k] = (v >= (float)SENT) ? (float)SENT : v;
        }
#pragma unroll
        for (int k = 0; k < 16; ++k) {
            float v = mB[k];
            tile[(8 + zB) * TSTR + 8 + iB + k] = (v >= (float)SENT) ? (float)SENT : v;
        }
        __syncthreads();
    }
    {   // ---- phase Z ----
        const int yA = tid % 128, iA = (tid / 128) * 16;
        const int cB = tid + 384;
        const int yB = cB % 128, iB = (cB / 128) * 16;
        edt_chunk<TSTR, ZD>(&tile[8 * TSTR + 8 + yA], iA, mA);
        edt_chunk<TSTR, ZD>(&tile[8 * TSTR + 8 + yB], iB, mB);
        __syncthreads();
#pragma unroll
        for (int k = 0; k < 16; ++k) {
            float v = mA[k];
            tile[(8 + iA + k) * TSTR + 8 + yA] = (v >= (float)SENT) ? (float)SENT : v;
        }
#pragma unroll
        for (int k = 0; k < 16; ++k) {
            float v = mB[k];
            tile[(8 + iB + k) * TSTR + 8 + yB] = (v >= (float)SENT) ? (float)SENT : v;
        }
        __syncthreads();
    }
    unsigned int* op = (unsigned int*)(out + (size_t)lv * NV + (size_t)x * SXX);
    for (int o = tid; o < SXX / 2; o += 384) {
        int e = o * 2;
        int y = e / ZD, z = e - y * ZD;
        unsigned int u0 = (unsigned int)tile[(8 + z) * TSTR + 8 + y];
        unsigned int u1 = (unsigned int)tile[(9 + z) * TSTR + 8 + y];
        op[o] = u0 | (u1 << 16);
    }
}

// ---------------- accum: 2-voxel vectorized, both batches in one grid ------
__global__ __launch_bounds__(256) void k_accum_batch(const unsigned short* __restrict__ vols,
                                                     const int* __restrict__ gt,
                                                     const float* __restrict__ net,
                                                     const int* __restrict__ flags,
                                                     double* __restrict__ partials,
                                                     int batch0) {
    const int b = batch0 + blockIdx.y;
    double ls = 0.0;
    const int* g = gt + (size_t)b * NV;
    const float* nb = net + (size_t)b * 4 * NV;
    const unsigned short* vb = vols + (size_t)blockIdx.y * 6 * NV;
    const int fbits = flags[b];
    const int NP = NV / 2;
    for (int p = blockIdx.x * 256 + threadIdx.x; p < NP; p += 1024 * 256) {
        const int idx = p * 2;
        float2 v0 = *(const float2*)(nb + idx);
        float2 v1 = *(const float2*)(nb + NV + idx);
        float2 v2 = *(const float2*)(nb + 2 * NV + idx);
        float2 v3 = *(const float2*)(nb + 3 * NV + idx);

        float mxa = fmaxf(fmaxf(v0.x, v1.x), fmaxf(v2.x, v3.x));
        float mxb = fmaxf(fmaxf(v0.y, v1.y), fmaxf(v2.y, v3.y));
        float e1a = __expf(v1.x - mxa), e2a = __expf(v2.x - mxa), e3a = __expf(v3.x - mxa);
        float e1b = __expf(v1.y - mxb), e2b = __expf(v2.y - mxb), e3b = __expf(v3.y - mxb);
        float sa = __expf(v0.x - mxa) + e1a + e2a + e3a;
        float sb = __expf(v0.y - mxb) + e1b + e2b + e3b;
        float ia = __frcp_rn(sa);
        float ib = __frcp_rn(sb);

        const int zp = p % 48;              // voxel z = 2*zp, 2*zp+1
        const int yy = (p / 48) & 127;
        const int xx = p / 6144;
        int2 gg  = *(const int2*)(g + idx);
        int2 gxm = (xx > 0)   ? *(const int2*)(g + idx - SXX) : gg;
        int2 gxp = (xx < 127) ? *(const int2*)(g + idx + SXX) : gg;
        int2 gym = (yy > 0)   ? *(const int2*)(g + idx - ZD)  : gg;
        int2 gyp = (yy < 127) ? *(const int2*)(g + idx + ZD)  : gg;
        int zm0 = (zp > 0)  ? g[idx - 1] : gg.x;
        int zp1 = (zp < 47) ? g[idx + 2] : gg.y;

        float acc = 0.0f;
#pragma unroll
        for (int ci = 1; ci <= 3; ++ci) {
            if ((fbits >> ci) & 1) {
                ushort2 dp = *(const ushort2*)(vb + (size_t)(2 * ci - 2) * NV + idx);
                ushort2 dn = *(const ushort2*)(vb + (size_t)(2 * ci - 1) * NV + idx);
                float ea = (ci == 1) ? e1a : ((ci == 2) ? e2a : e3a);
                float eb = (ci == 1) ? e1b : ((ci == 2) ? e2b : e3b);
                bool bndA = (gg.x == ci) &&
                            (gxm.x != ci || gxp.x != ci || gym.x != ci ||
                             gyp.x != ci || zm0 != ci || gg.y != ci);
                bool bndB = (gg.y == ci) &&
                            (gxm.y != ci || gxp.y != ci || gym.y != ci ||
                             gyp.y != ci || gg.x != ci || zp1 != ci);
                float phiA = bndA ? 0.0f : (sqrtf((float)dn.x) - sqrtf((float)dp.x));
                float phiB = bndB ? 0.0f : (sqrtf((float)dn.y) - sqrtf((float)dp.y));
                acc += (ea * ia) * phiA + (eb * ib) * phiB;
            }
        }
        ls += (double)acc;
    }
    __shared__ double sd[256];
    sd[threadIdx.x] = ls;
    __syncthreads();
    for (int off = 128; off > 0; off >>= 1) {
        if (threadIdx.x < off) sd[threadIdx.x] += sd[threadIdx.x + off];
        __syncthreads();
    }
    if (threadIdx.x == 0) partials[(size_t)b * 1024 + blockIdx.x] = sd[0];
}

// -------------------------------------------------------------- reduce ----
__global__ void k_reduce(const double* __restrict__ partials, int n,
                         float* __restrict__ out) {
    __shared__ double sd[256];
    double ls = 0.0;
    for (int i = threadIdx.x; i < n; i += 256) ls += partials[i];
    sd[threadIdx.x] = ls;
    __syncthreads();
    for (int off = 128; off > 0; off >>= 1) {
        if (threadIdx.x < off) sd[threadIdx.x] += sd[threadIdx.x + off];
        __syncthreads();
    }
    if (threadIdx.x == 0) out[0] = (float)(sd[0] / 9437184.0);
}

// ---------------------------------------------------------------- launch ----
extern "C" void kernel_launch(void* const* d_in, const int* in_sizes, int n_in,
                              void* d_out, int out_size, void* d_ws, size_t ws_size,
                              hipStream_t stream) {
    const float* net = (const float*)d_in[0];
    const int*   gt  = (const int*)d_in[1];
    float* out = (float*)d_out;
    char* ws = (char*)d_ws;

    const size_t xbufB1 = (size_t)6 * NV;                        // u8,  9.4 MB
    const size_t zbufB1 = (size_t)6 * NV * sizeof(unsigned short); // u16, 18.9 MB
    const size_t tail   = (size_t)2048 * sizeof(double) + 64;

    const int nb = (ws_size >= 2 * (xbufB1 + zbufB1) + tail) ? 2 : 1;

    unsigned char*  xbuf = (unsigned char*)ws;
    unsigned short* zbuf = (unsigned short*)(ws + (size_t)nb * xbufB1);
    double* partials = (double*)(ws + (size_t)nb * (xbufB1 + zbufB1));
    int* flags = (int*)((char*)partials + 2048 * sizeof(double));

    hipLaunchKernelGGL(k_zero_flags, dim3(1), dim3(64), 0, stream, flags);

    for (int b0 = 0; b0 < 2; b0 += nb) {
        hipLaunchKernelGGL(k_scan_x, dim3(SXX / 64, nb), dim3(256), 0, stream,
                           gt, xbuf, flags, b0);
        hipLaunchKernelGGL(k_pass_yz, dim3(XD, 6 * nb), dim3(384), 0, stream,
                           xbuf, zbuf);
        hipLaunchKernelGGL(k_accum_batch, dim3(1024, nb), dim3(256), 0, stream,
                           zbuf, gt, net, flags, partials, b0);
    }
    hipLaunchKernelGGL(k_reduce, dim3(1), dim3(256), 0, stream, partials,
                       2048, out);
}

// Round 7
// 107.707 us; speedup vs baseline: 6.2305x; 1.0652x over previous
//
#include <hip/hip_runtime.h>
#include <math.h>

#define XD 128
#define YD 128
#define ZD 96
#define NV (XD*YD*ZD)      /* 1572864 voxels per volume */
#define SXX (YD*ZD)        /* x-stride = 12288 */
#define SENT 49152         /* sentinel: > any real d^2 (max 41283) */
#define TW 146             /* u16 tile row stride; 73 dwords, 73%32=9 coprime */

// ---------------------------------------------------------------- flags ----
__global__ void k_zero_flags(int* flags) {
    if (threadIdx.x < 8) flags[threadIdx.x] = 0;
}

// -------------------------------------------- pass X: binary run-length scan
// 6 waves: wave w6 = 2*c+s owns the (class c+1, sign s) scan for all 64 lines
// (fwd and bwd N/I scans are independent). Output u8 distance packed 4 lines
// per u32 store. Also accumulates class-presence bits into flags[batch].
__global__ __launch_bounds__(384) void k_scan_x(const int* __restrict__ gt,
                                                unsigned char* __restrict__ out,
                                                int* __restrict__ flags,
                                                int batch0) {
    const int bb  = blockIdx.y;
    const int myb = batch0 + bb;
    const int tid = threadIdx.x;
    const int l   = tid & 63;
    const int w6  = tid >> 6;            // 0..5
    const int lq0 = blockIdx.x * 64;

    __shared__ unsigned char gtile[64 * 132];
    __shared__ unsigned char dtile[6 * 64 * 132];
    __shared__ int blkbits;
    if (tid == 0) blkbits = 0;

    int mybits = 0;
    const int* gp = gt + (size_t)myb * NV + lq0 + l;
    for (int j = w6; j < XD; j += 6) {
        int g = gp[(size_t)j * SXX];
        mybits |= 1 << g;
        gtile[l * 132 + j] = (unsigned char)g;
    }
#pragma unroll
    for (int off = 32; off; off >>= 1) mybits |= __shfl_xor(mybits, off);
    __syncthreads();
    if ((tid & 63) == 0) atomicOr(&blkbits, mybits);

    {   // thread = (slot w6, line l); slot = 2*c + s
        const int ci = (w6 >> 1) + 1;
        const int s  = w6 & 1;
        const unsigned char* gl = gtile + l * 132;
        unsigned char* dd = dtile + w6 * (64 * 132) + l * 132;
        int cnt = 200;
        for (int j = 0; j < XD; ++j) {
            bool zero = s ? (gl[j] == ci) : (gl[j] != ci);
            cnt = zero ? 0 : ((cnt < 200) ? cnt + 1 : 200);
            dd[j] = (unsigned char)cnt;
        }
        cnt = 200;
        for (int j = XD - 1; j >= 0; --j) {
            bool zero = s ? (gl[j] == ci) : (gl[j] != ci);
            cnt = zero ? 0 : ((cnt < 200) ? cnt + 1 : 200);
            if (cnt < dd[j]) dd[j] = (unsigned char)cnt;
        }
    }
    __syncthreads();
    if (tid == 0) atomicOr(&flags[myb], blkbits);

    // output: pack 4 consecutive lines (same j) into one u32 store
    for (int it = tid; it < 6 * 128 * 16; it += 384) {
        int slot = it >> 11;             // /2048
        int rem  = it & 2047;
        int j    = rem >> 4;
        int lq4  = rem & 15;
        const unsigned char* dd = dtile + slot * (64 * 132);
        unsigned int u = 0;
#pragma unroll
        for (int q = 0; q < 4; ++q)
            u |= (unsigned int)dd[(lq4 * 4 + q) * 132 + j] << (8 * q);
        *(unsigned int*)(out + (size_t)(bb * 6 + slot) * NV +
                         (size_t)j * SXX + lq0 + lq4 * 4) = u;
    }
}

// ------------- EDT fast path: t<=8 on a 32-float register window -----------
// Centers at r[8..23]. Bit-exact vs brute force (excluded candidates strictly
// greater; all values exact small ints in f32).
__device__ __forceinline__ bool edt_fast(const float r[32], float m[16]) {
#pragma unroll
    for (int k = 0; k < 16; ++k) m[k] = r[k + 8];
#pragma unroll
    for (int t = 1; t <= 4; ++t) {
        const float t2 = (float)(t * t);
#pragma unroll
        for (int k = 0; k < 16; ++k)
            m[k] = fminf(m[k], fminf(r[k + 8 - t], r[k + 8 + t]) + t2);
    }
    float mm = m[0];
#pragma unroll
    for (int k = 1; k < 16; ++k) mm = fmaxf(mm, m[k]);
    if (__all(mm <= 16.0f)) return true;
#pragma unroll
    for (int t = 5; t <= 8; ++t) {
        const float t2 = (float)(t * t);
#pragma unroll
        for (int k = 0; k < 16; ++k)
            m[k] = fminf(m[k], fminf(r[k + 8 - t], r[k + 8 + t]) + t2);
    }
    mm = m[0];
#pragma unroll
    for (int k = 1; k < 16; ++k) mm = fmaxf(mm, m[k]);
    return __all(mm <= 64.0f) != 0;
}

// ------------- EDT slow path (rare): clamped LDS u16 reads, t>=9 -----------
// p0 points at element j=0 (value at j is p0[j*STRIDE]); valid j in [-8,L+7].
template<int STRIDE, int L>
__device__ void edt_slow(const unsigned short* __restrict__ p0, int i0,
                         float m[16]) {
    int t = 9;
    bool done = false;
    while (!done && t < L) {
        for (int u = 0; u < 4; ++u, ++t) {
            float t2 = (float)(t * t);
#pragma unroll
            for (int k = 0; k < 16; ++k) {
                int jm = i0 + k - t; if (jm < -8) jm = -8;
                int jp = i0 + k + t; if (jp > L + 7) jp = L + 7;
                m[k] = fminf(m[k], fminf((float)p0[jm * STRIDE],
                                         (float)p0[jp * STRIDE]) + t2);
            }
        }
        float mm = m[0];
#pragma unroll
        for (int k = 1; k < 16; ++k) mm = fmaxf(mm, m[k]);
        done = __all(mm <= (float)((t - 1) * (t - 1))) != 0;
    }
}

// ------------- fused Y+Z pass: one x-plane resident in LDS as u16 ----------
// Tile [112][146] u16 (32.7 KB -> 4 blocks/CU): rows = 8 pad | 96 z | 8 pad,
// cols = 8 pad | 128 y | 10 pad. Pad value 0xFFFF (65535 > SENT: never wins).
// Phase Y lanes share i0/vary z (bank stride 9, conflict-free); phase Z lanes
// vary y (consecutive banks). 2 chunks per thread per phase.
__global__ __launch_bounds__(384, 6) void k_pass_yz(const unsigned char* __restrict__ in,
                                                    unsigned short* __restrict__ out) {
    const int lv  = blockIdx.y;          // volume slot
    const int x   = blockIdx.x;
    const int tid = threadIdx.x;
    __shared__ unsigned short tile[112 * TW];

    {   // fill everything with pad, then overwrite the data region
        unsigned int* t32 = (unsigned int*)tile;
        for (int i = tid; i < (112 * TW) / 2; i += 384) t32[i] = 0xFFFFFFFFu;
    }
    __syncthreads();
    const unsigned int* ip =
        (const unsigned int*)(in + (size_t)lv * NV + (size_t)x * SXX);
    for (int o = tid; o < SXX / 4; o += 384) {            // u8 d -> u16 d^2
        unsigned int v = ip[o];
        int e = o * 4;
        int y = e / ZD, z = e - y * ZD;                    // z..z+3, same y
        unsigned short* dst = &tile[(8 + z) * TW + 8 + y];
#pragma unroll
        for (int q = 0; q < 4; ++q) {
            unsigned int d = (v >> (8 * q)) & 0xFFu;
            dst[q * TW] = (d > 127u) ? (unsigned short)SENT
                                     : (unsigned short)(d * d);
        }
    }
    __syncthreads();

    float mA[16], mB[16];
    {   // ---- phase Y ----
        const int zA = tid % 96, iA = (tid / 96) * 16;
        const int cB = tid + 384;
        const int zB = cB % 96, iB = (cB / 96) * 16;
        unsigned short* rpA = &tile[(8 + zA) * TW];
        unsigned short* rpB = &tile[(8 + zB) * TW];
        float r[32];
        {
            const unsigned int* wp = (const unsigned int*)(rpA + iA);
#pragma unroll
            for (int q = 0; q < 16; ++q) {
                unsigned int u = wp[q];
                r[2 * q] = (float)(u & 0xFFFFu); r[2 * q + 1] = (float)(u >> 16);
            }
        }
        if (!edt_fast(r, mA)) edt_slow<1, YD>(rpA + 8, iA, mA);
        {
            const unsigned int* wp = (const unsigned int*)(rpB + iB);
#pragma unroll
            for (int q = 0; q < 16; ++q) {
                unsigned int u = wp[q];
                r[2 * q] = (float)(u & 0xFFFFu); r[2 * q + 1] = (float)(u >> 16);
            }
        }
        if (!edt_fast(r, mB)) edt_slow<1, YD>(rpB + 8, iB, mB);
        __syncthreads();                 // all window reads done
        unsigned int* opA = (unsigned int*)(rpA + 8 + iA);
        unsigned int* opB = (unsigned int*)(rpB + 8 + iB);
#pragma unroll
        for (int q = 0; q < 8; ++q) {
            unsigned int u0 = (unsigned int)fminf(mA[2 * q],     (float)SENT);
            unsigned int u1 = (unsigned int)fminf(mA[2 * q + 1], (float)SENT);
            opA[q] = u0 | (u1 << 16);
        }
#pragma unroll
        for (int q = 0; q < 8; ++q) {
            unsigned int u0 = (unsigned int)fminf(mB[2 * q],     (float)SENT);
            unsigned int u1 = (unsigned int)fminf(mB[2 * q + 1], (float)SENT);
            opB[q] = u0 | (u1 << 16);
        }
        __syncthreads();
    }
    {   // ---- phase Z ----
        const int yA = tid % 128, iA = (tid / 128) * 16;
        const int cB = tid + 384;
        const int yB = cB % 128, iB = (cB / 128) * 16;
        unsigned short* pA = &tile[8 * TW + 8 + yA];   // z=j at pA[j*TW]
        unsigned short* pB = &tile[8 * TW + 8 + yB];
        float r[32];
#pragma unroll
        for (int w = 0; w < 32; ++w) r[w] = (float)pA[(iA - 8 + w) * TW];
        if (!edt_fast(r, mA)) edt_slow<TW, ZD>(pA, iA, mA);
#pragma unroll
        for (int w = 0; w < 32; ++w) r[w] = (float)pB[(iB - 8 + w) * TW];
        if (!edt_fast(r, mB)) edt_slow<TW, ZD>(pB, iB, mB);
        __syncthreads();
#pragma unroll
        for (int k = 0; k < 16; ++k)
            pA[(iA + k) * TW] = (unsigned short)fminf(mA[k], (float)SENT);
#pragma unroll
        for (int k = 0; k < 16; ++k)
            pB[(iB + k) * TW] = (unsigned short)fminf(mB[k], (float)SENT);
        __syncthreads();
    }
    unsigned int* op = (unsigned int*)(out + (size_t)lv * NV + (size_t)x * SXX);
    for (int o = tid; o < SXX / 2; o += 384) {
        int e = o * 2;
        int y = e / ZD, z = e - y * ZD;
        unsigned int a = tile[(8 + z) * TW + 8 + y];
        unsigned int b = tile[(9 + z) * TW + 8 + y];
        op[o] = a | (b << 16);
    }
}

// ---------------- accum: 2-voxel vectorized, both batches in one grid ------
__global__ __launch_bounds__(256) void k_accum_batch(const unsigned short* __restrict__ vols,
                                                     const int* __restrict__ gt,
                                                     const float* __restrict__ net,
                                                     const int* __restrict__ flags,
                                                     double* __restrict__ partials,
                                                     int batch0) {
    const int b = batch0 + blockIdx.y;
    double ls = 0.0;
    const int* g = gt + (size_t)b * NV;
    const float* nb = net + (size_t)b * 4 * NV;
    const unsigned short* vb = vols + (size_t)blockIdx.y * 6 * NV;
    const int fbits = flags[b];
    const int NP = NV / 2;
    for (int p = blockIdx.x * 256 + threadIdx.x; p < NP; p += 1024 * 256) {
        const int idx = p * 2;
        float2 v0 = *(const float2*)(nb + idx);
        float2 v1 = *(const float2*)(nb + NV + idx);
        float2 v2 = *(const float2*)(nb + 2 * NV + idx);
        float2 v3 = *(const float2*)(nb + 3 * NV + idx);

        float mxa = fmaxf(fmaxf(v0.x, v1.x), fmaxf(v2.x, v3.x));
        float mxb = fmaxf(fmaxf(v0.y, v1.y), fmaxf(v2.y, v3.y));
        float e1a = __expf(v1.x - mxa), e2a = __expf(v2.x - mxa), e3a = __expf(v3.x - mxa);
        float e1b = __expf(v1.y - mxb), e2b = __expf(v2.y - mxb), e3b = __expf(v3.y - mxb);
        float sa = __expf(v0.x - mxa) + e1a + e2a + e3a;
        float sb = __expf(v0.y - mxb) + e1b + e2b + e3b;
        float ia = __frcp_rn(sa);
        float ib = __frcp_rn(sb);

        const int zp = p % 48;              // voxel z = 2*zp, 2*zp+1
        const int yy = (p / 48) & 127;
        const int xx = p / 6144;
        int2 gg  = *(const int2*)(g + idx);
        int2 gxm = (xx > 0)   ? *(const int2*)(g + idx - SXX) : gg;
        int2 gxp = (xx < 127) ? *(const int2*)(g + idx + SXX) : gg;
        int2 gym = (yy > 0)   ? *(const int2*)(g + idx - ZD)  : gg;
        int2 gyp = (yy < 127) ? *(const int2*)(g + idx + ZD)  : gg;
        int zm0 = (zp > 0)  ? g[idx - 1] : gg.x;
        int zp1 = (zp < 47) ? g[idx + 2] : gg.y;

        float acc = 0.0f;
#pragma unroll
        for (int ci = 1; ci <= 3; ++ci) {
            if ((fbits >> ci) & 1) {
                ushort2 dp = *(const ushort2*)(vb + (size_t)(2 * ci - 2) * NV + idx);
                ushort2 dn = *(const ushort2*)(vb + (size_t)(2 * ci - 1) * NV + idx);
                float ea = (ci == 1) ? e1a : ((ci == 2) ? e2a : e3a);
                float eb = (ci == 1) ? e1b : ((ci == 2) ? e2b : e3b);
                bool bndA = (gg.x == ci) &&
                            (gxm.x != ci || gxp.x != ci || gym.x != ci ||
                             gyp.x != ci || zm0 != ci || gg.y != ci);
                bool bndB = (gg.y == ci) &&
                            (gxm.y != ci || gxp.y != ci || gym.y != ci ||
                             gyp.y != ci || gg.x != ci || zp1 != ci);
                float phiA = bndA ? 0.0f : (sqrtf((float)dn.x) - sqrtf((float)dp.x));
                float phiB = bndB ? 0.0f : (sqrtf((float)dn.y) - sqrtf((float)dp.y));
                acc += (ea * ia) * phiA + (eb * ib) * phiB;
            }
        }
        ls += (double)acc;
    }
    __shared__ double sd[256];
    sd[threadIdx.x] = ls;
    __syncthreads();
    for (int off = 128; off > 0; off >>= 1) {
        if (threadIdx.x < off) sd[threadIdx.x] += sd[threadIdx.x + off];
        __syncthreads();
    }
    if (threadIdx.x == 0) partials[(size_t)b * 1024 + blockIdx.x] = sd[0];
}

// -------------------------------------------------------------- reduce ----
__global__ void k_reduce(const double* __restrict__ partials, int n,
                         float* __restrict__ out) {
    __shared__ double sd[256];
    double ls = 0.0;
    for (int i = threadIdx.x; i < n; i += 256) ls += partials[i];
    sd[threadIdx.x] = ls;
    __syncthreads();
    for (int off = 128; off > 0; off >>= 1) {
        if (threadIdx.x < off) sd[threadIdx.x] += sd[threadIdx.x + off];
        __syncthreads();
    }
    if (threadIdx.x == 0) out[0] = (float)(sd[0] / 9437184.0);
}

// ---------------------------------------------------------------- launch ----
extern "C" void kernel_launch(void* const* d_in, const int* in_sizes, int n_in,
                              void* d_out, int out_size, void* d_ws, size_t ws_size,
                              hipStream_t stream) {
    const float* net = (const float*)d_in[0];
    const int*   gt  = (const int*)d_in[1];
    float* out = (float*)d_out;
    char* ws = (char*)d_ws;

    const size_t xbufB1 = (size_t)6 * NV;                          // u8,  9.4 MB
    const size_t zbufB1 = (size_t)6 * NV * sizeof(unsigned short); // u16, 18.9 MB
    const size_t tail   = (size_t)2048 * sizeof(double) + 64;

    const int nb = (ws_size >= 2 * (xbufB1 + zbufB1) + tail) ? 2 : 1;

    unsigned char*  xbuf = (unsigned char*)ws;
    unsigned short* zbuf = (unsigned short*)(ws + (size_t)nb * xbufB1);
    double* partials = (double*)(ws + (size_t)nb * (xbufB1 + zbufB1));
    int* flags = (int*)((char*)partials + 2048 * sizeof(double));

    hipLaunchKernelGGL(k_zero_flags, dim3(1), dim3(64), 0, stream, flags);

    for (int b0 = 0; b0 < 2; b0 += nb) {
        hipLaunchKernelGGL(k_scan_x, dim3(SXX / 64, nb), dim3(384), 0, stream,
                           gt, xbuf, flags, b0);
        hipLaunchKernelGGL(k_pass_yz, dim3(XD, 6 * nb), dim3(384), 0, stream,
                           xbuf, zbuf);
        hipLaunchKernelGGL(k_accum_batch, dim3(1024, nb), dim3(256), 0, stream,
                           zbuf, gt, net, flags, partials, b0);
    }
    hipLaunchKernelGGL(k_reduce, dim3(1), dim3(256), 0, stream, partials,
                       2048, out);
}

// Round 8
// 100.668 us; speedup vs baseline: 6.6662x; 1.0699x over previous
//
#include <hip/hip_runtime.h>
#include <math.h>

#define XD 128
#define YD 128
#define ZD 96
#define NV (XD*YD*ZD)      /* 1572864 voxels per volume */
#define SXX (YD*ZD)        /* x-stride = 12288 */
#define SENT 49152         /* sentinel: > any real d^2 (max 41283) */
#define TW2 114            /* u16 cols: 8 pad | 96 z | 10 pad; 57 dw, 57%32=25 */
#define TDW (TW2/2)        /* 57 dwords per row */
#define TROWS 144          /* rows: 8 pad | 128 y | 8 pad */

// ---------------------------------------------------------------- flags ----
__global__ void k_zero_flags(int* flags) {
    if (threadIdx.x < 8) flags[threadIdx.x] = 0;
}

// -------------------------------------------- pass X: binary run-length scan
// 6 waves: wave w6 = 2*c+s owns the (class c+1, sign s) scan for all 64 lines.
// Output u8 distance packed 4 lines per u32 store. Also accumulates
// class-presence bits into flags[batch].
__global__ __launch_bounds__(384) void k_scan_x(const int* __restrict__ gt,
                                                unsigned char* __restrict__ out,
                                                int* __restrict__ flags,
                                                int batch0) {
    const int bb  = blockIdx.y;
    const int myb = batch0 + bb;
    const int tid = threadIdx.x;
    const int l   = tid & 63;
    const int w6  = tid >> 6;            // 0..5
    const int lq0 = blockIdx.x * 64;

    __shared__ unsigned char gtile[64 * 132];
    __shared__ unsigned char dtile[6 * 64 * 132];
    __shared__ int blkbits;
    if (tid == 0) blkbits = 0;

    int mybits = 0;
    const int* gp = gt + (size_t)myb * NV + lq0 + l;
    for (int j = w6; j < XD; j += 6) {
        int g = gp[(size_t)j * SXX];
        mybits |= 1 << g;
        gtile[l * 132 + j] = (unsigned char)g;
    }
#pragma unroll
    for (int off = 32; off; off >>= 1) mybits |= __shfl_xor(mybits, off);
    __syncthreads();
    if ((tid & 63) == 0) atomicOr(&blkbits, mybits);

    {   // thread = (slot w6, line l); slot = 2*c + s
        const int ci = (w6 >> 1) + 1;
        const int s  = w6 & 1;
        const unsigned char* gl = gtile + l * 132;
        unsigned char* dd = dtile + w6 * (64 * 132) + l * 132;
        int cnt = 200;
        for (int j = 0; j < XD; ++j) {
            bool zero = s ? (gl[j] == ci) : (gl[j] != ci);
            cnt = zero ? 0 : ((cnt < 200) ? cnt + 1 : 200);
            dd[j] = (unsigned char)cnt;
        }
        cnt = 200;
        for (int j = XD - 1; j >= 0; --j) {
            bool zero = s ? (gl[j] == ci) : (gl[j] != ci);
            cnt = zero ? 0 : ((cnt < 200) ? cnt + 1 : 200);
            if (cnt < dd[j]) dd[j] = (unsigned char)cnt;
        }
    }
    __syncthreads();
    if (tid == 0) atomicOr(&flags[myb], blkbits);

    // output: pack 4 consecutive lines (same j) into one u32 store
    for (int it = tid; it < 6 * 128 * 16; it += 384) {
        int slot = it >> 11;
        int rem  = it & 2047;
        int j    = rem >> 4;
        int lq4  = rem & 15;
        const unsigned char* dd = dtile + slot * (64 * 132);
        unsigned int u = 0;
#pragma unroll
        for (int q = 0; q < 4; ++q)
            u |= (unsigned int)dd[(lq4 * 4 + q) * 132 + j] << (8 * q);
        *(unsigned int*)(out + (size_t)(bb * 6 + slot) * NV +
                         (size_t)j * SXX + lq0 + lq4 * 4) = u;
    }
}

// ------------- EDT fast path: t<=8 on a 32-float register window -----------
// Centers at r[8..23]. Returns true if converged (no slow path needed).
// Bit-exact vs brute force: excluded candidates strictly greater.
__device__ __forceinline__ bool edt_fast(const float r[32], float m[16]) {
#pragma unroll
    for (int k = 0; k < 16; ++k) m[k] = r[k + 8];
#pragma unroll
    for (int t = 1; t <= 4; ++t) {
        const float t2 = (float)(t * t);
#pragma unroll
        for (int k = 0; k < 16; ++k)
            m[k] = fminf(m[k], fminf(r[k + 8 - t], r[k + 8 + t]) + t2);
    }
    float mm = m[0];
#pragma unroll
    for (int k = 1; k < 16; ++k) mm = fmaxf(mm, m[k]);
    if (__all(mm <= 16.0f)) return true;
#pragma unroll
    for (int t = 5; t <= 8; ++t) {
        const float t2 = (float)(t * t);
#pragma unroll
        for (int k = 0; k < 16; ++k)
            m[k] = fminf(m[k], fminf(r[k + 8 - t], r[k + 8 + t]) + t2);
    }
    mm = m[0];
#pragma unroll
    for (int k = 1; k < 16; ++k) mm = fmaxf(mm, m[k]);
    return __all(mm <= 64.0f) != 0;
}

// ------------- EDT slow path (rare): clamped LDS u16 reads, t>=9 -----------
// p0 points at element j=0 (value at j is p0[j*STRIDE]); valid j in [-8,L+7].
template<int STRIDE, int L>
__device__ void edt_slow(const unsigned short* __restrict__ p0, int i0,
                         float m[16]) {
    int t = 9;
    bool done = false;
    while (!done && t < L) {
        for (int u = 0; u < 4; ++u, ++t) {
            float t2 = (float)(t * t);
#pragma unroll
            for (int k = 0; k < 16; ++k) {
                int jm = i0 + k - t; if (jm < -8) jm = -8;
                int jp = i0 + k + t; if (jp > L + 7) jp = L + 7;
                m[k] = fminf(m[k], fminf((float)p0[jm * STRIDE],
                                         (float)p0[jp * STRIDE]) + t2);
            }
        }
        float mm = m[0];
#pragma unroll
        for (int k = 1; k < 16; ++k) mm = fmaxf(mm, m[k]);
        done = __all(mm <= (float)((t - 1) * (t - 1))) != 0;
    }
}

// ------------- fused Y+Z pass: x-plane in LDS as u16 [y][z] ----------------
// Tile [144 rows = 8|128y|8][114 cols = 8|96z|10] u16, row = 57 dwords
// (57%32=25, coprime). All phases bank-conflict-free by construction:
//   staging: 8 consecutive dwords/lane; phase-Y: lane-consecutive u16
//   (64 lanes = 32 dwords = all banks); phase-Z: stride-57-dword (coprime);
//   output: direct dword copy. Pad = 0xFFFF (never wins; result clamped).
__global__ __launch_bounds__(384, 6) void k_pass_yz(const unsigned char* __restrict__ in,
                                                    unsigned short* __restrict__ out) {
    const int lv  = blockIdx.y;          // volume slot
    const int x   = blockIdx.x;
    const int tid = threadIdx.x;
    __shared__ unsigned short tile[TROWS * TW2];
    unsigned int* t32 = (unsigned int*)tile;

    // pad rows (y pads): rows 0..7 and 136..143, full width
    for (int i = tid; i < 16 * TDW; i += 384) {
        int r = i / TDW, c = i - r * TDW;
        int row = (r < 8) ? r : 128 + r;
        t32[row * TDW + c] = 0xFFFFFFFFu;
    }
    // pad cols in data rows: dwords 0..3 (left) and 52..56 (right)
    for (int i = tid; i < 128 * 9; i += 384) {
        int r = i / 9, c = i - r * 9;
        int col = (c < 4) ? c : (48 + c);
        t32[(8 + r) * TDW + col] = 0xFFFFFFFFu;
    }
    // stage: u8 d -> u16 d^2; 16 z per lane (same y), 8 dword writes
    const uint4* ip = (const uint4*)(in + (size_t)lv * NV + (size_t)x * SXX);
    for (int o = tid; o < SXX / 16; o += 384) {
        uint4 v = ip[o];
        int e = o * 16;
        int y = e / ZD, z = e - y * ZD;           // z multiple of 16, same y
        unsigned int base = (8 + y) * TDW + (8 + z) / 2;
        unsigned int vv[4] = {v.x, v.y, v.z, v.w};
#pragma unroll
        for (int q = 0; q < 4; ++q) {
            unsigned int b0 = vv[q] & 255u, b1 = (vv[q] >> 8) & 255u;
            unsigned int b2 = (vv[q] >> 16) & 255u, b3 = vv[q] >> 24;
            t32[base + 2 * q] = (b0 > 127u ? SENT : b0 * b0) |
                                ((b1 > 127u ? SENT : b1 * b1) << 16);
            t32[base + 2 * q + 1] = (b2 > 127u ? SENT : b2 * b2) |
                                    ((b3 > 127u ? SENT : b3 * b3) << 16);
        }
    }
    __syncthreads();

    float mA[16], mB[16];
    {   // ---- phase Y (EDT along y; lanes vary z: conflict-free) ----
        const int zA = tid % 96, iA = (tid / 96) * 16;
        const int tB = tid + 384;
        const int zB = tB % 96, iB = (tB / 96) * 16;
        float r[32];
#pragma unroll
        for (int w = 0; w < 32; ++w) r[w] = (float)tile[(iA + w) * TW2 + 8 + zA];
        if (!edt_fast(r, mA)) edt_slow<TW2, YD>(&tile[8 * TW2 + 8 + zA], iA, mA);
#pragma unroll
        for (int w = 0; w < 32; ++w) r[w] = (float)tile[(iB + w) * TW2 + 8 + zB];
        if (!edt_fast(r, mB)) edt_slow<TW2, YD>(&tile[8 * TW2 + 8 + zB], iB, mB);
        __syncthreads();                 // all window reads done
#pragma unroll
        for (int k = 0; k < 16; ++k)
            tile[(8 + iA + k) * TW2 + 8 + zA] =
                (unsigned short)fminf(mA[k], (float)SENT);
#pragma unroll
        for (int k = 0; k < 16; ++k)
            tile[(8 + iB + k) * TW2 + 8 + zB] =
                (unsigned short)fminf(mB[k], (float)SENT);
        __syncthreads();
    }
    {   // ---- phase Z (EDT along z; rows contiguous, stride-57 coprime) ----
        const int yA = tid % 128, iA = (tid / 128) * 16;
        const int tB = tid + 384;
        const int yB = tB % 128, iB = (tB / 128) * 16;
        float r[32];
        {
            const unsigned int* wp = &t32[(8 + yA) * TDW + iA / 2];  // u16 col iA
#pragma unroll
            for (int q = 0; q < 16; ++q) {
                unsigned int u = wp[q];
                r[2 * q] = (float)(u & 0xFFFFu);
                r[2 * q + 1] = (float)(u >> 16);
            }
        }
        if (!edt_fast(r, mA)) edt_slow<1, ZD>(&tile[(8 + yA) * TW2 + 8], iA, mA);
        {
            const unsigned int* wp = &t32[(8 + yB) * TDW + iB / 2];
#pragma unroll
            for (int q = 0; q < 16; ++q) {
                unsigned int u = wp[q];
                r[2 * q] = (float)(u & 0xFFFFu);
                r[2 * q + 1] = (float)(u >> 16);
            }
        }
        if (!edt_fast(r, mB)) edt_slow<1, ZD>(&tile[(8 + yB) * TW2 + 8], iB, mB);
        __syncthreads();
        {
            unsigned int* wp = &t32[(8 + yA) * TDW + (8 + iA) / 2];
#pragma unroll
            for (int q = 0; q < 8; ++q) {
                unsigned int u0 = (unsigned int)fminf(mA[2 * q],     (float)SENT);
                unsigned int u1 = (unsigned int)fminf(mA[2 * q + 1], (float)SENT);
                wp[q] = u0 | (u1 << 16);
            }
        }
        {
            unsigned int* wp = &t32[(8 + yB) * TDW + (8 + iB) / 2];
#pragma unroll
            for (int q = 0; q < 8; ++q) {
                unsigned int u0 = (unsigned int)fminf(mB[2 * q],     (float)SENT);
                unsigned int u1 = (unsigned int)fminf(mB[2 * q + 1], (float)SENT);
                wp[q] = u0 | (u1 << 16);
            }
        }
        __syncthreads();
    }
    // output: direct dword copy (z-pairs contiguous), uint4 stores
    uint4* op = (uint4*)(out + (size_t)lv * NV + (size_t)x * SXX);
    for (int o = tid; o < SXX / 8; o += 384) {
        int e = o * 8;
        int y = e / ZD, z = e - y * ZD;           // z multiple of 8, same y
        const unsigned int* sp = &t32[(8 + y) * TDW + (8 + z) / 2];
        uint4 v; v.x = sp[0]; v.y = sp[1]; v.z = sp[2]; v.w = sp[3];
        op[o] = v;
    }
}

// ---------------- accum: 2-voxel vectorized, both batches in one grid ------
__global__ __launch_bounds__(256) void k_accum_batch(const unsigned short* __restrict__ vols,
                                                     const int* __restrict__ gt,
                                                     const float* __restrict__ net,
                                                     const int* __restrict__ flags,
                                                     double* __restrict__ partials,
                                                     int batch0) {
    const int b = batch0 + blockIdx.y;
    double ls = 0.0;
    const int* g = gt + (size_t)b * NV;
    const float* nb = net + (size_t)b * 4 * NV;
    const unsigned short* vb = vols + (size_t)blockIdx.y * 6 * NV;
    const int fbits = flags[b];
    const int NP = NV / 2;
    for (int p = blockIdx.x * 256 + threadIdx.x; p < NP; p += 1024 * 256) {
        const int idx = p * 2;
        float2 v0 = *(const float2*)(nb + idx);
        float2 v1 = *(const float2*)(nb + NV + idx);
        float2 v2 = *(const float2*)(nb + 2 * NV + idx);
        float2 v3 = *(const float2*)(nb + 3 * NV + idx);

        float mxa = fmaxf(fmaxf(v0.x, v1.x), fmaxf(v2.x, v3.x));
        float mxb = fmaxf(fmaxf(v0.y, v1.y), fmaxf(v2.y, v3.y));
        float e1a = __expf(v1.x - mxa), e2a = __expf(v2.x - mxa), e3a = __expf(v3.x - mxa);
        float e1b = __expf(v1.y - mxb), e2b = __expf(v2.y - mxb), e3b = __expf(v3.y - mxb);
        float sa = __expf(v0.x - mxa) + e1a + e2a + e3a;
        float sb = __expf(v0.y - mxb) + e1b + e2b + e3b;
        float ia = __frcp_rn(sa);
        float ib = __frcp_rn(sb);

        const int zp = p % 48;              // voxel z = 2*zp, 2*zp+1
        const int yy = (p / 48) & 127;
        const int xx = p / 6144;
        int2 gg  = *(const int2*)(g + idx);
        int2 gxm = (xx > 0)   ? *(const int2*)(g + idx - SXX) : gg;
        int2 gxp = (xx < 127) ? *(const int2*)(g + idx + SXX) : gg;
        int2 gym = (yy > 0)   ? *(const int2*)(g + idx - ZD)  : gg;
        int2 gyp = (yy < 127) ? *(const int2*)(g + idx + ZD)  : gg;
        int zm0 = (zp > 0)  ? g[idx - 1] : gg.x;
        int zp1 = (zp < 47) ? g[idx + 2] : gg.y;

        float acc = 0.0f;
#pragma unroll
        for (int ci = 1; ci <= 3; ++ci) {
            if ((fbits >> ci) & 1) {
                ushort2 dp = *(const ushort2*)(vb + (size_t)(2 * ci - 2) * NV + idx);
                ushort2 dn = *(const ushort2*)(vb + (size_t)(2 * ci - 1) * NV + idx);
                float ea = (ci == 1) ? e1a : ((ci == 2) ? e2a : e3a);
                float eb = (ci == 1) ? e1b : ((ci == 2) ? e2b : e3b);
                bool bndA = (gg.x == ci) &&
                            (gxm.x != ci || gxp.x != ci || gym.x != ci ||
                             gyp.x != ci || zm0 != ci || gg.y != ci);
                bool bndB = (gg.y == ci) &&
                            (gxm.y != ci || gxp.y != ci || gym.y != ci ||
                             gyp.y != ci || gg.x != ci || zp1 != ci);
                float phiA = bndA ? 0.0f : (sqrtf((float)dn.x) - sqrtf((float)dp.x));
                float phiB = bndB ? 0.0f : (sqrtf((float)dn.y) - sqrtf((float)dp.y));
                acc += (ea * ia) * phiA + (eb * ib) * phiB;
            }
        }
        ls += (double)acc;
    }
    __shared__ double sd[256];
    sd[threadIdx.x] = ls;
    __syncthreads();
    for (int off = 128; off > 0; off >>= 1) {
        if (threadIdx.x < off) sd[threadIdx.x] += sd[threadIdx.x + off];
        __syncthreads();
    }
    if (threadIdx.x == 0) partials[(size_t)b * 1024 + blockIdx.x] = sd[0];
}

// -------------------------------------------------------------- reduce ----
__global__ void k_reduce(const double* __restrict__ partials, int n,
                         float* __restrict__ out) {
    __shared__ double sd[256];
    double ls = 0.0;
    for (int i = threadIdx.x; i < n; i += 256) ls += partials[i];
    sd[threadIdx.x] = ls;
    __syncthreads();
    for (int off = 128; off > 0; off >>= 1) {
        if (threadIdx.x < off) sd[threadIdx.x] += sd[threadIdx.x + off];
        __syncthreads();
    }
    if (threadIdx.x == 0) out[0] = (float)(sd[0] / 9437184.0);
}

// ---------------------------------------------------------------- launch ----
extern "C" void kernel_launch(void* const* d_in, const int* in_sizes, int n_in,
                              void* d_out, int out_size, void* d_ws, size_t ws_size,
                              hipStream_t stream) {
    const float* net = (const float*)d_in[0];
    const int*   gt  = (const int*)d_in[1];
    float* out = (float*)d_out;
    char* ws = (char*)d_ws;

    const size_t xbufB1 = (size_t)6 * NV;                          // u8,  9.4 MB
    const size_t zbufB1 = (size_t)6 * NV * sizeof(unsigned short); // u16, 18.9 MB
    const size_t tail   = (size_t)2048 * sizeof(double) + 64;

    const int nb = (ws_size >= 2 * (xbufB1 + zbufB1) + tail) ? 2 : 1;

    unsigned char*  xbuf = (unsigned char*)ws;
    unsigned short* zbuf = (unsigned short*)(ws + (size_t)nb * xbufB1);
    double* partials = (double*)(ws + (size_t)nb * (xbufB1 + zbufB1));
    int* flags = (int*)((char*)partials + 2048 * sizeof(double));

    hipLaunchKernelGGL(k_zero_flags, dim3(1), dim3(64), 0, stream, flags);

    for (int b0 = 0; b0 < 2; b0 += nb) {
        hipLaunchKernelGGL(k_scan_x, dim3(SXX / 64, nb), dim3(384), 0, stream,
                           gt, xbuf, flags, b0);
        hipLaunchKernelGGL(k_pass_yz, dim3(XD, 6 * nb), dim3(384), 0, stream,
                           xbuf, zbuf);
        hipLaunchKernelGGL(k_accum_batch, dim3(1024, nb), dim3(256), 0, stream,
                           zbuf, gt, net, flags, partials, b0);
    }
    hipLaunchKernelGGL(k_reduce, dim3(1), dim3(256), 0, stream, partials,
                       2048, out);
}

// Round 9
// 90.333 us; speedup vs baseline: 7.4289x; 1.1144x over previous
//
#include <hip/hip_runtime.h>
#include <math.h>

#define XD 128
#define YD 128
#define ZD 96
#define NV (XD*YD*ZD)      /* 1572864 voxels per volume */
#define SXX (YD*ZD)        /* x-stride = 12288 */
#define SENT 49152         /* sentinel: > any real d^2 (max 41283) */
#define TW2 114            /* u16 cols: 8 pad | 96 z | 10 pad; 57 dw, 57%32=25 */
#define TDW (TW2/2)        /* 57 dwords per row */
#define TROWS 144          /* rows: 8 pad | 128 y | 8 pad */

// ---------------------------------------------------------------- flags ----
__global__ void k_zero_flags(int* flags) {
    if (threadIdx.x < 8) flags[threadIdx.x] = 0;
}

// -------------------------------------------- pass X: binary run-length scan
// 6 waves: wave w6 = 2*c+s owns the (class c+1, sign s) scan for all 64 lines.
// Register-resident: line loaded once into 32 dwords (LDS stride 33, coprime),
// fwd/bwd scans fully unrolled on registers (no in-loop LDS), result written
// back as 32 dword stores. Output u8 distance packed 4 lines per u32 store.
__global__ __launch_bounds__(384) void k_scan_x(const int* __restrict__ gt,
                                                unsigned char* __restrict__ out,
                                                int* __restrict__ flags,
                                                int batch0) {
    const int bb  = blockIdx.y;
    const int myb = batch0 + bb;
    const int tid = threadIdx.x;
    const int l   = tid & 63;
    const int w6  = tid >> 6;            // 0..5
    const int lq0 = blockIdx.x * 64;

    __shared__ unsigned char gtile[64 * 132];
    __shared__ unsigned char dtile[6 * 64 * 132];
    __shared__ int blkbits;
    if (tid == 0) blkbits = 0;

    int mybits = 0;
    const int* gp = gt + (size_t)myb * NV + lq0 + l;
    for (int j = w6; j < XD; j += 6) {
        int g = gp[(size_t)j * SXX];
        mybits |= 1 << g;
        gtile[l * 132 + j] = (unsigned char)g;
    }
#pragma unroll
    for (int off = 32; off; off >>= 1) mybits |= __shfl_xor(mybits, off);
    __syncthreads();
    if ((tid & 63) == 0) atomicOr(&blkbits, mybits);

    {   // thread = (slot w6, line l); slot = 2*c + s; all in registers
        const unsigned int ci = (unsigned int)((w6 >> 1) + 1);
        const int s = w6 & 1;
        unsigned int G[32], D[32];
        const unsigned int* grow = (const unsigned int*)gtile + l * 33;
#pragma unroll
        for (int q = 0; q < 32; ++q) G[q] = grow[q];

        int cnt = 200;
#pragma unroll
        for (int q = 0; q < 32; ++q) {
            unsigned int u = G[q], dv = 0;
#pragma unroll
            for (int b = 0; b < 4; ++b) {
                unsigned int gv = (u >> (8 * b)) & 255u;
                bool zero = s ? (gv == ci) : (gv != ci);
                cnt = zero ? 0 : ((cnt < 200) ? cnt + 1 : 200);
                dv |= (unsigned int)cnt << (8 * b);
            }
            D[q] = dv;
        }
        cnt = 200;
#pragma unroll
        for (int q = 31; q >= 0; --q) {
            unsigned int u = G[q], dv = D[q];
#pragma unroll
            for (int b = 3; b >= 0; --b) {
                unsigned int gv = (u >> (8 * b)) & 255u;
                bool zero = s ? (gv == ci) : (gv != ci);
                cnt = zero ? 0 : ((cnt < 200) ? cnt + 1 : 200);
                unsigned int old = (dv >> (8 * b)) & 255u;
                unsigned int nbv = ((unsigned int)cnt < old) ? (unsigned int)cnt : old;
                dv = (dv & ~(255u << (8 * b))) | (nbv << (8 * b));
            }
            D[q] = dv;
        }
        unsigned int* drow = (unsigned int*)(dtile + w6 * (64 * 132)) + l * 33;
#pragma unroll
        for (int q = 0; q < 32; ++q) drow[q] = D[q];
    }
    __syncthreads();
    if (tid == 0) atomicOr(&flags[myb], blkbits);

    // output: pack 4 consecutive lines (same j) into one u32 store
    for (int it = tid; it < 6 * 128 * 16; it += 384) {
        int slot = it >> 11;
        int rem  = it & 2047;
        int j    = rem >> 4;
        int lq4  = rem & 15;
        const unsigned char* dd = dtile + slot * (64 * 132);
        unsigned int u = 0;
#pragma unroll
        for (int q = 0; q < 4; ++q)
            u |= (unsigned int)dd[(lq4 * 4 + q) * 132 + j] << (8 * q);
        *(unsigned int*)(out + (size_t)(bb * 6 + slot) * NV +
                         (size_t)j * SXX + lq0 + lq4 * 4) = u;
    }
}

// ------------- EDT fast path: t<=8 on a 32-float register window -----------
// Centers at r[8..23]. Returns true if converged (no slow path needed).
// Bit-exact vs brute force: excluded candidates strictly greater.
__device__ __forceinline__ bool edt_fast(const float r[32], float m[16]) {
#pragma unroll
    for (int k = 0; k < 16; ++k) m[k] = r[k + 8];
#pragma unroll
    for (int t = 1; t <= 4; ++t) {
        const float t2 = (float)(t * t);
#pragma unroll
        for (int k = 0; k < 16; ++k)
            m[k] = fminf(m[k], fminf(r[k + 8 - t], r[k + 8 + t]) + t2);
    }
    float mm = m[0];
#pragma unroll
    for (int k = 1; k < 16; ++k) mm = fmaxf(mm, m[k]);
    if (__all(mm <= 16.0f)) return true;
#pragma unroll
    for (int t = 5; t <= 8; ++t) {
        const float t2 = (float)(t * t);
#pragma unroll
        for (int k = 0; k < 16; ++k)
            m[k] = fminf(m[k], fminf(r[k + 8 - t], r[k + 8 + t]) + t2);
    }
    mm = m[0];
#pragma unroll
    for (int k = 1; k < 16; ++k) mm = fmaxf(mm, m[k]);
    return __all(mm <= 64.0f) != 0;
}

// ------------- EDT slow path (rare): clamped LDS u16 reads, t>=9 -----------
// p0 points at element j=0 (value at j is p0[j*STRIDE]); valid j in [-8,L+7].
template<int STRIDE, int L>
__device__ void edt_slow(const unsigned short* __restrict__ p0, int i0,
                         float m[16]) {
    int t = 9;
    bool done = false;
    while (!done && t < L) {
        for (int u = 0; u < 4; ++u, ++t) {
            float t2 = (float)(t * t);
#pragma unroll
            for (int k = 0; k < 16; ++k) {
                int jm = i0 + k - t; if (jm < -8) jm = -8;
                int jp = i0 + k + t; if (jp > L + 7) jp = L + 7;
                m[k] = fminf(m[k], fminf((float)p0[jm * STRIDE],
                                         (float)p0[jp * STRIDE]) + t2);
            }
        }
        float mm = m[0];
#pragma unroll
        for (int k = 1; k < 16; ++k) mm = fmaxf(mm, m[k]);
        done = __all(mm <= (float)((t - 1) * (t - 1))) != 0;
    }
}

// ------------- fused Y+Z pass: x-plane in LDS as u16 [y][z] ----------------
// Tile [144 rows = 8|128y|8][114 cols = 8|96z|10] u16, row = 57 dwords
// (57%32=25, coprime). All phases bank-conflict-free by construction.
__global__ __launch_bounds__(384, 6) void k_pass_yz(const unsigned char* __restrict__ in,
                                                    unsigned short* __restrict__ out) {
    const int lv  = blockIdx.y;          // volume slot
    const int x   = blockIdx.x;
    const int tid = threadIdx.x;
    __shared__ unsigned short tile[TROWS * TW2];
    unsigned int* t32 = (unsigned int*)tile;

    // pad rows (y pads): rows 0..7 and 136..143, full width
    for (int i = tid; i < 16 * TDW; i += 384) {
        int r = i / TDW, c = i - r * TDW;
        int row = (r < 8) ? r : 128 + r;
        t32[row * TDW + c] = 0xFFFFFFFFu;
    }
    // pad cols in data rows: dwords 0..3 (left) and 52..56 (right)
    for (int i = tid; i < 128 * 9; i += 384) {
        int r = i / 9, c = i - r * 9;
        int col = (c < 4) ? c : (48 + c);
        t32[(8 + r) * TDW + col] = 0xFFFFFFFFu;
    }
    // stage: u8 d -> u16 d^2; 16 z per lane (same y), 8 dword writes
    const uint4* ip = (const uint4*)(in + (size_t)lv * NV + (size_t)x * SXX);
    for (int o = tid; o < SXX / 16; o += 384) {
        uint4 v = ip[o];
        int e = o * 16;
        int y = e / ZD, z = e - y * ZD;           // z multiple of 16, same y
        unsigned int base = (8 + y) * TDW + (8 + z) / 2;
        unsigned int vv[4] = {v.x, v.y, v.z, v.w};
#pragma unroll
        for (int q = 0; q < 4; ++q) {
            unsigned int b0 = vv[q] & 255u, b1 = (vv[q] >> 8) & 255u;
            unsigned int b2 = (vv[q] >> 16) & 255u, b3 = vv[q] >> 24;
            t32[base + 2 * q] = (b0 > 127u ? SENT : b0 * b0) |
                                ((b1 > 127u ? SENT : b1 * b1) << 16);
            t32[base + 2 * q + 1] = (b2 > 127u ? SENT : b2 * b2) |
                                    ((b3 > 127u ? SENT : b3 * b3) << 16);
        }
    }
    __syncthreads();

    float mA[16], mB[16];
    {   // ---- phase Y (EDT along y; lanes vary z: conflict-free) ----
        const int zA = tid % 96, iA = (tid / 96) * 16;
        const int tB = tid + 384;
        const int zB = tB % 96, iB = (tB / 96) * 16;
        float r[32];
#pragma unroll
        for (int w = 0; w < 32; ++w) r[w] = (float)tile[(iA + w) * TW2 + 8 + zA];
        if (!edt_fast(r, mA)) edt_slow<TW2, YD>(&tile[8 * TW2 + 8 + zA], iA, mA);
#pragma unroll
        for (int w = 0; w < 32; ++w) r[w] = (float)tile[(iB + w) * TW2 + 8 + zB];
        if (!edt_fast(r, mB)) edt_slow<TW2, YD>(&tile[8 * TW2 + 8 + zB], iB, mB);
        __syncthreads();                 // all window reads done
#pragma unroll
        for (int k = 0; k < 16; ++k)
            tile[(8 + iA + k) * TW2 + 8 + zA] =
                (unsigned short)fminf(mA[k], (float)SENT);
#pragma unroll
        for (int k = 0; k < 16; ++k)
            tile[(8 + iB + k) * TW2 + 8 + zB] =
                (unsigned short)fminf(mB[k], (float)SENT);
        __syncthreads();
    }
    {   // ---- phase Z (EDT along z; rows contiguous, stride-57 coprime) ----
        const int yA = tid % 128, iA = (tid / 128) * 16;
        const int tB = tid + 384;
        const int yB = tB % 128, iB = (tB / 128) * 16;
        float r[32];
        {
            const unsigned int* wp = &t32[(8 + yA) * TDW + iA / 2];  // u16 col iA
#pragma unroll
            for (int q = 0; q < 16; ++q) {
                unsigned int u = wp[q];
                r[2 * q] = (float)(u & 0xFFFFu);
                r[2 * q + 1] = (float)(u >> 16);
            }
        }
        if (!edt_fast(r, mA)) edt_slow<1, ZD>(&tile[(8 + yA) * TW2 + 8], iA, mA);
        {
            const unsigned int* wp = &t32[(8 + yB) * TDW + iB / 2];
#pragma unroll
            for (int q = 0; q < 16; ++q) {
                unsigned int u = wp[q];
                r[2 * q] = (float)(u & 0xFFFFu);
                r[2 * q + 1] = (float)(u >> 16);
            }
        }
        if (!edt_fast(r, mB)) edt_slow<1, ZD>(&tile[(8 + yB) * TW2 + 8], iB, mB);
        __syncthreads();
        {
            unsigned int* wp = &t32[(8 + yA) * TDW + (8 + iA) / 2];
#pragma unroll
            for (int q = 0; q < 8; ++q) {
                unsigned int u0 = (unsigned int)fminf(mA[2 * q],     (float)SENT);
                unsigned int u1 = (unsigned int)fminf(mA[2 * q + 1], (float)SENT);
                wp[q] = u0 | (u1 << 16);
            }
        }
        {
            unsigned int* wp = &t32[(8 + yB) * TDW + (8 + iB) / 2];
#pragma unroll
            for (int q = 0; q < 8; ++q) {
                unsigned int u0 = (unsigned int)fminf(mB[2 * q],     (float)SENT);
                unsigned int u1 = (unsigned int)fminf(mB[2 * q + 1], (float)SENT);
                wp[q] = u0 | (u1 << 16);
            }
        }
        __syncthreads();
    }
    // output: direct dword copy (z-pairs contiguous), uint4 stores
    uint4* op = (uint4*)(out + (size_t)lv * NV + (size_t)x * SXX);
    for (int o = tid; o < SXX / 8; o += 384) {
        int e = o * 8;
        int y = e / ZD, z = e - y * ZD;           // z multiple of 8, same y
        const unsigned int* sp = &t32[(8 + y) * TDW + (8 + z) / 2];
        uint4 v; v.x = sp[0]; v.y = sp[1]; v.z = sp[2]; v.w = sp[3];
        op[o] = v;
    }
}

// ---------------- accum: 2-voxel vectorized, both batches in one grid ------
__global__ __launch_bounds__(256) void k_accum_batch(const unsigned short* __restrict__ vols,
                                                     const int* __restrict__ gt,
                                                     const float* __restrict__ net,
                                                     const int* __restrict__ flags,
                                                     double* __restrict__ partials,
                                                     int batch0) {
    const int b = batch0 + blockIdx.y;
    double ls = 0.0;
    const int* g = gt + (size_t)b * NV;
    const float* nb = net + (size_t)b * 4 * NV;
    const unsigned short* vb = vols + (size_t)blockIdx.y * 6 * NV;
    const int fbits = flags[b];
    const int NP = NV / 2;
    for (int p = blockIdx.x * 256 + threadIdx.x; p < NP; p += 1024 * 256) {
        const int idx = p * 2;
        float2 v0 = *(const float2*)(nb + idx);
        float2 v1 = *(const float2*)(nb + NV + idx);
        float2 v2 = *(const float2*)(nb + 2 * NV + idx);
        float2 v3 = *(const float2*)(nb + 3 * NV + idx);

        float mxa = fmaxf(fmaxf(v0.x, v1.x), fmaxf(v2.x, v3.x));
        float mxb = fmaxf(fmaxf(v0.y, v1.y), fmaxf(v2.y, v3.y));
        float e1a = __expf(v1.x - mxa), e2a = __expf(v2.x - mxa), e3a = __expf(v3.x - mxa);
        float e1b = __expf(v1.y - mxb), e2b = __expf(v2.y - mxb), e3b = __expf(v3.y - mxb);
        float sa = __expf(v0.x - mxa) + e1a + e2a + e3a;
        float sb = __expf(v0.y - mxb) + e1b + e2b + e3b;
        float ia = __frcp_rn(sa);
        float ib = __frcp_rn(sb);

        const int zp = p % 48;              // voxel z = 2*zp, 2*zp+1
        const int yy = (p / 48) & 127;
        const int xx = p / 6144;
        int2 gg  = *(const int2*)(g + idx);
        int2 gxm = (xx > 0)   ? *(const int2*)(g + idx - SXX) : gg;
        int2 gxp = (xx < 127) ? *(const int2*)(g + idx + SXX) : gg;
        int2 gym = (yy > 0)   ? *(const int2*)(g + idx - ZD)  : gg;
        int2 gyp = (yy < 127) ? *(const int2*)(g + idx + ZD)  : gg;
        int zm0 = (zp > 0)  ? g[idx - 1] : gg.x;
        int zp1 = (zp < 47) ? g[idx + 2] : gg.y;

        float acc = 0.0f;
#pragma unroll
        for (int ci = 1; ci <= 3; ++ci) {
            if ((fbits >> ci) & 1) {
                ushort2 dp = *(const ushort2*)(vb + (size_t)(2 * ci - 2) * NV + idx);
                ushort2 dn = *(const ushort2*)(vb + (size_t)(2 * ci - 1) * NV + idx);
                float ea = (ci == 1) ? e1a : ((ci == 2) ? e2a : e3a);
                float eb = (ci == 1) ? e1b : ((ci == 2) ? e2b : e3b);
                bool bndA = (gg.x == ci) &&
                            (gxm.x != ci || gxp.x != ci || gym.x != ci ||
                             gyp.x != ci || zm0 != ci || gg.y != ci);
                bool bndB = (gg.y == ci) &&
                            (gxm.y != ci || gxp.y != ci || gym.y != ci ||
                             gyp.y != ci || gg.x != ci || zp1 != ci);
                float phiA = bndA ? 0.0f : (sqrtf((float)dn.x) - sqrtf((float)dp.x));
                float phiB = bndB ? 0.0f : (sqrtf((float)dn.y) - sqrtf((float)dp.y));
                acc += (ea * ia) * phiA + (eb * ib) * phiB;
            }
        }
        ls += (double)acc;
    }
    __shared__ double sd[256];
    sd[threadIdx.x] = ls;
    __syncthreads();
    for (int off = 128; off > 0; off >>= 1) {
        if (threadIdx.x < off) sd[threadIdx.x] += sd[threadIdx.x + off];
        __syncthreads();
    }
    if (threadIdx.x == 0) partials[(size_t)b * 1024 + blockIdx.x] = sd[0];
}

// -------------------------------------------------------------- reduce ----
__global__ void k_reduce(const double* __restrict__ partials, int n,
                         float* __restrict__ out) {
    __shared__ double sd[256];
    double ls = 0.0;
    for (int i = threadIdx.x; i < n; i += 256) ls += partials[i];
    sd[threadIdx.x] = ls;
    __syncthreads();
    for (int off = 128; off > 0; off >>= 1) {
        if (threadIdx.x < off) sd[threadIdx.x] += sd[threadIdx.x + off];
        __syncthreads();
    }
    if (threadIdx.x == 0) out[0] = (float)(sd[0] / 9437184.0);
}

// ---------------------------------------------------------------- launch ----
extern "C" void kernel_launch(void* const* d_in, const int* in_sizes, int n_in,
                              void* d_out, int out_size, void* d_ws, size_t ws_size,
                              hipStream_t stream) {
    const float* net = (const float*)d_in[0];
    const int*   gt  = (const int*)d_in[1];
    float* out = (float*)d_out;
    char* ws = (char*)d_ws;

    const size_t xbufB1 = (size_t)6 * NV;                          // u8,  9.4 MB
    const size_t zbufB1 = (size_t)6 * NV * sizeof(unsigned short); // u16, 18.9 MB
    const size_t tail   = (size_t)2048 * sizeof(double) + 64;

    const int nb = (ws_size >= 2 * (xbufB1 + zbufB1) + tail) ? 2 : 1;

    unsigned char*  xbuf = (unsigned char*)ws;
    unsigned short* zbuf = (unsigned short*)(ws + (size_t)nb * xbufB1);
    double* partials = (double*)(ws + (size_t)nb * (xbufB1 + zbufB1));
    int* flags = (int*)((char*)partials + 2048 * sizeof(double));

    hipLaunchKernelGGL(k_zero_flags, dim3(1), dim3(64), 0, stream, flags);

    for (int b0 = 0; b0 < 2; b0 += nb) {
        hipLaunchKernelGGL(k_scan_x, dim3(SXX / 64, nb), dim3(384), 0, stream,
                           gt, xbuf, flags, b0);
        hipLaunchKernelGGL(k_pass_yz, dim3(XD, 6 * nb), dim3(384), 0, stream,
                           xbuf, zbuf);
        hipLaunchKernelGGL(k_accum_batch, dim3(1024, nb), dim3(256), 0, stream,
                           zbuf, gt, net, flags, partials, b0);
    }
    hipLaunchKernelGGL(k_reduce, dim3(1), dim3(256), 0, stream, partials,
                       2048, out);
}

// Round 10
// 89.088 us; speedup vs baseline: 7.5327x; 1.0140x over previous
//
#include <hip/hip_runtime.h>
#include <math.h>

#define XD 128
#define YD 128
#define ZD 96
#define NV (XD*YD*ZD)      /* 1572864 voxels per volume */
#define SXX (YD*ZD)        /* x-stride = 12288 */
#define SENT 49152         /* sentinel: > any real d^2 (max 41283) */
#define TW2 114            /* u16 cols: 8 pad | 96 z | 10 pad; 57 dw, 57%32=25 */
#define TDW (TW2/2)        /* 57 dwords per row */
#define TROWS 144          /* rows: 8 pad | 128 y | 8 pad */

// ---------------------------------------------------------------- flags ----
__global__ void k_zero_flags(int* flags) {
    if (threadIdx.x < 8) flags[threadIdx.x] = 0;
}

// -------------------------------------------- pass X: binary run-length scan
// 6 waves: wave w6 = 2*c+s owns the (class c+1, sign s) scan for all 64 lines.
// Register-resident scan (line = 32 dwords from gtile, stride 33, coprime).
// Output transpose done IN-WAVE: 4x4 byte transpose per 4-lane group via
// shfl_xor + v_perm (no dtile, no LDS in the output path). LDS = gtile only.
__global__ __launch_bounds__(384) void k_scan_x(const int* __restrict__ gt,
                                                unsigned char* __restrict__ out,
                                                int* __restrict__ flags,
                                                int batch0) {
    const int bb  = blockIdx.y;
    const int myb = batch0 + bb;
    const int tid = threadIdx.x;
    const int l   = tid & 63;
    const int w6  = tid >> 6;            // 0..5
    const int lq0 = blockIdx.x * 64;

    __shared__ unsigned char gtile[64 * 132];
    __shared__ int blkbits;
    if (tid == 0) blkbits = 0;

    int mybits = 0;
    const int* gp = gt + (size_t)myb * NV + lq0 + l;
    for (int j = w6; j < XD; j += 6) {
        int g = gp[(size_t)j * SXX];
        mybits |= 1 << g;
        gtile[l * 132 + j] = (unsigned char)g;
    }
#pragma unroll
    for (int off = 32; off; off >>= 1) mybits |= __shfl_xor(mybits, off);
    __syncthreads();
    if ((tid & 63) == 0) atomicOr(&blkbits, mybits);

    unsigned int D[32];
    {   // thread = (slot w6, line l); slot = 2*c + s; all in registers
        const unsigned int ci = (unsigned int)((w6 >> 1) + 1);
        const int s = w6 & 1;
        unsigned int G[32];
        const unsigned int* grow = (const unsigned int*)gtile + l * 33;
#pragma unroll
        for (int q = 0; q < 32; ++q) G[q] = grow[q];

        int cnt = 200;
#pragma unroll
        for (int q = 0; q < 32; ++q) {
            unsigned int u = G[q], dv = 0;
#pragma unroll
            for (int b = 0; b < 4; ++b) {
                unsigned int gv = (u >> (8 * b)) & 255u;
                bool zero = s ? (gv == ci) : (gv != ci);
                cnt = zero ? 0 : ((cnt < 200) ? cnt + 1 : 200);
                dv |= (unsigned int)cnt << (8 * b);
            }
            D[q] = dv;
        }
        cnt = 200;
#pragma unroll
        for (int q = 31; q >= 0; --q) {
            unsigned int u = G[q], dv = D[q];
#pragma unroll
            for (int b = 3; b >= 0; --b) {
                unsigned int gv = (u >> (8 * b)) & 255u;
                bool zero = s ? (gv == ci) : (gv != ci);
                cnt = zero ? 0 : ((cnt < 200) ? cnt + 1 : 200);
                unsigned int old = (dv >> (8 * b)) & 255u;
                unsigned int nbv = ((unsigned int)cnt < old) ? (unsigned int)cnt : old;
                dv = (dv & ~(255u << (8 * b))) | (nbv << (8 * b));
            }
            D[q] = dv;
        }
    }
    __syncthreads();                     // blkbits complete
    if (tid == 0) atomicOr(&flags[myb], blkbits);

    // in-wave 4x4 byte transpose (groups of 4 lanes = 4 lines) + store.
    // After the butterfly, lane 4i+r holds the u32 for column j=4q+r with
    // byte k = line 4i+k — identical packing to the old dtile gather.
    {
        const int r = l & 3;
        unsigned char* ob = out + (size_t)(bb * 6 + w6) * NV + lq0 + (l & ~3);
#pragma unroll
        for (int q = 0; q < 32; ++q) {
            unsigned int A = D[q];
            unsigned int Bv = (unsigned int)__shfl_xor((int)A, 1);
            unsigned int t = (r & 1)
                ? __builtin_amdgcn_perm(A, Bv, 0x07030501u)   // [B1,A1,B3,A3]
                : __builtin_amdgcn_perm(A, Bv, 0x02060004u);  // [A0,B0,A2,B2]
            unsigned int Cv = (unsigned int)__shfl_xor((int)t, 2);
            unsigned int y = (r & 2)
                ? __builtin_amdgcn_perm(t, Cv, 0x07060302u)   // [C2,C3,t2,t3]
                : __builtin_amdgcn_perm(t, Cv, 0x01000504u);  // [t0,t1,C0,C1]
            *(unsigned int*)(ob + (size_t)(4 * q + r) * SXX) = y;
        }
    }
}

// ------------- EDT fast path: t<=8 on a 32-float register window -----------
// Centers at r[8..23]. Returns true if converged (no slow path needed).
// Bit-exact vs brute force: excluded candidates strictly greater.
__device__ __forceinline__ bool edt_fast(const float r[32], float m[16]) {
#pragma unroll
    for (int k = 0; k < 16; ++k) m[k] = r[k + 8];
#pragma unroll
    for (int t = 1; t <= 4; ++t) {
        const float t2 = (float)(t * t);
#pragma unroll
        for (int k = 0; k < 16; ++k)
            m[k] = fminf(m[k], fminf(r[k + 8 - t], r[k + 8 + t]) + t2);
    }
    float mm = m[0];
#pragma unroll
    for (int k = 1; k < 16; ++k) mm = fmaxf(mm, m[k]);
    if (__all(mm <= 16.0f)) return true;
#pragma unroll
    for (int t = 5; t <= 8; ++t) {
        const float t2 = (float)(t * t);
#pragma unroll
        for (int k = 0; k < 16; ++k)
            m[k] = fminf(m[k], fminf(r[k + 8 - t], r[k + 8 + t]) + t2);
    }
    mm = m[0];
#pragma unroll
    for (int k = 1; k < 16; ++k) mm = fmaxf(mm, m[k]);
    return __all(mm <= 64.0f) != 0;
}

// ------------- EDT slow path (rare): clamped LDS u16 reads, t>=9 -----------
// p0 points at element j=0 (value at j is p0[j*STRIDE]); valid j in [-8,L+7].
template<int STRIDE, int L>
__device__ void edt_slow(const unsigned short* __restrict__ p0, int i0,
                         float m[16]) {
    int t = 9;
    bool done = false;
    while (!done && t < L) {
        for (int u = 0; u < 4; ++u, ++t) {
            float t2 = (float)(t * t);
#pragma unroll
            for (int k = 0; k < 16; ++k) {
                int jm = i0 + k - t; if (jm < -8) jm = -8;
                int jp = i0 + k + t; if (jp > L + 7) jp = L + 7;
                m[k] = fminf(m[k], fminf((float)p0[jm * STRIDE],
                                         (float)p0[jp * STRIDE]) + t2);
            }
        }
        float mm = m[0];
#pragma unroll
        for (int k = 1; k < 16; ++k) mm = fmaxf(mm, m[k]);
        done = __all(mm <= (float)((t - 1) * (t - 1))) != 0;
    }
}

// ------------- fused Y+Z pass: x-plane in LDS as u16 [y][z] ----------------
// Tile [144 rows = 8|128y|8][114 cols = 8|96z|10] u16, row = 57 dwords
// (57%32=25, coprime). All phases bank-conflict-free by construction.
__global__ __launch_bounds__(384, 6) void k_pass_yz(const unsigned char* __restrict__ in,
                                                    unsigned short* __restrict__ out) {
    const int lv  = blockIdx.y;          // volume slot
    const int x   = blockIdx.x;
    const int tid = threadIdx.x;
    __shared__ unsigned short tile[TROWS * TW2];
    unsigned int* t32 = (unsigned int*)tile;

    // pad rows (y pads): rows 0..7 and 136..143, full width
    for (int i = tid; i < 16 * TDW; i += 384) {
        int r = i / TDW, c = i - r * TDW;
        int row = (r < 8) ? r : 128 + r;
        t32[row * TDW + c] = 0xFFFFFFFFu;
    }
    // pad cols in data rows: dwords 0..3 (left) and 52..56 (right)
    for (int i = tid; i < 128 * 9; i += 384) {
        int r = i / 9, c = i - r * 9;
        int col = (c < 4) ? c : (48 + c);
        t32[(8 + r) * TDW + col] = 0xFFFFFFFFu;
    }
    // stage: u8 d -> u16 d^2; 16 z per lane (same y), 8 dword writes
    const uint4* ip = (const uint4*)(in + (size_t)lv * NV + (size_t)x * SXX);
    for (int o = tid; o < SXX / 16; o += 384) {
        uint4 v = ip[o];
        int e = o * 16;
        int y = e / ZD, z = e - y * ZD;           // z multiple of 16, same y
        unsigned int base = (8 + y) * TDW + (8 + z) / 2;
        unsigned int vv[4] = {v.x, v.y, v.z, v.w};
#pragma unroll
        for (int q = 0; q < 4; ++q) {
            unsigned int b0 = vv[q] & 255u, b1 = (vv[q] >> 8) & 255u;
            unsigned int b2 = (vv[q] >> 16) & 255u, b3 = vv[q] >> 24;
            t32[base + 2 * q] = (b0 > 127u ? SENT : b0 * b0) |
                                ((b1 > 127u ? SENT : b1 * b1) << 16);
            t32[base + 2 * q + 1] = (b2 > 127u ? SENT : b2 * b2) |
                                    ((b3 > 127u ? SENT : b3 * b3) << 16);
        }
    }
    __syncthreads();

    float mA[16], mB[16];
    {   // ---- phase Y (EDT along y; lanes vary z: conflict-free) ----
        const int zA = tid % 96, iA = (tid / 96) * 16;
        const int tB = tid + 384;
        const int zB = tB % 96, iB = (tB / 96) * 16;
        float r[32];
#pragma unroll
        for (int w = 0; w < 32; ++w) r[w] = (float)tile[(iA + w) * TW2 + 8 + zA];
        if (!edt_fast(r, mA)) edt_slow<TW2, YD>(&tile[8 * TW2 + 8 + zA], iA, mA);
#pragma unroll
        for (int w = 0; w < 32; ++w) r[w] = (float)tile[(iB + w) * TW2 + 8 + zB];
        if (!edt_fast(r, mB)) edt_slow<TW2, YD>(&tile[8 * TW2 + 8 + zB], iB, mB);
        __syncthreads();                 // all window reads done
#pragma unroll
        for (int k = 0; k < 16; ++k)
            tile[(8 + iA + k) * TW2 + 8 + zA] =
                (unsigned short)fminf(mA[k], (float)SENT);
#pragma unroll
        for (int k = 0; k < 16; ++k)
            tile[(8 + iB + k) * TW2 + 8 + zB] =
                (unsigned short)fminf(mB[k], (float)SENT);
        __syncthreads();
    }
    {   // ---- phase Z (EDT along z; rows contiguous, stride-57 coprime) ----
        const int yA = tid % 128, iA = (tid / 128) * 16;
        const int tB = tid + 384;
        const int yB = tB % 128, iB = (tB / 128) * 16;
        float r[32];
        {
            const unsigned int* wp = &t32[(8 + yA) * TDW + iA / 2];  // u16 col iA
#pragma unroll
            for (int q = 0; q < 16; ++q) {
                unsigned int u = wp[q];
                r[2 * q] = (float)(u & 0xFFFFu);
                r[2 * q + 1] = (float)(u >> 16);
            }
        }
        if (!edt_fast(r, mA)) edt_slow<1, ZD>(&tile[(8 + yA) * TW2 + 8], iA, mA);
        {
            const unsigned int* wp = &t32[(8 + yB) * TDW + iB / 2];
#pragma unroll
            for (int q = 0; q < 16; ++q) {
                unsigned int u = wp[q];
                r[2 * q] = (float)(u & 0xFFFFu);
                r[2 * q + 1] = (float)(u >> 16);
            }
        }
        if (!edt_fast(r, mB)) edt_slow<1, ZD>(&tile[(8 + yB) * TW2 + 8], iB, mB);
        __syncthreads();
        {
            unsigned int* wp = &t32[(8 + yA) * TDW + (8 + iA) / 2];
#pragma unroll
            for (int q = 0; q < 8; ++q) {
                unsigned int u0 = (unsigned int)fminf(mA[2 * q],     (float)SENT);
                unsigned int u1 = (unsigned int)fminf(mA[2 * q + 1], (float)SENT);
                wp[q] = u0 | (u1 << 16);
            }
        }
        {
            unsigned int* wp = &t32[(8 + yB) * TDW + (8 + iB) / 2];
#pragma unroll
            for (int q = 0; q < 8; ++q) {
                unsigned int u0 = (unsigned int)fminf(mB[2 * q],     (float)SENT);
                unsigned int u1 = (unsigned int)fminf(mB[2 * q + 1], (float)SENT);
                wp[q] = u0 | (u1 << 16);
            }
        }
        __syncthreads();
    }
    // output: direct dword copy (z-pairs contiguous), uint4 stores
    uint4* op = (uint4*)(out + (size_t)lv * NV + (size_t)x * SXX);
    for (int o = tid; o < SXX / 8; o += 384) {
        int e = o * 8;
        int y = e / ZD, z = e - y * ZD;           // z multiple of 8, same y
        const unsigned int* sp = &t32[(8 + y) * TDW + (8 + z) / 2];
        uint4 v; v.x = sp[0]; v.y = sp[1]; v.z = sp[2]; v.w = sp[3];
        op[o] = v;
    }
}

// ---------------- accum: 2-voxel vectorized, both batches in one grid ------
__global__ __launch_bounds__(256) void k_accum_batch(const unsigned short* __restrict__ vols,
                                                     const int* __restrict__ gt,
                                                     const float* __restrict__ net,
                                                     const int* __restrict__ flags,
                                                     double* __restrict__ partials,
                                                     int batch0) {
    const int b = batch0 + blockIdx.y;
    double ls = 0.0;
    const int* g = gt + (size_t)b * NV;
    const float* nb = net + (size_t)b * 4 * NV;
    const unsigned short* vb = vols + (size_t)blockIdx.y * 6 * NV;
    const int fbits = flags[b];
    const int NP = NV / 2;
    for (int p = blockIdx.x * 256 + threadIdx.x; p < NP; p += 1024 * 256) {
        const int idx = p * 2;
        float2 v0 = *(const float2*)(nb + idx);
        float2 v1 = *(const float2*)(nb + NV + idx);
        float2 v2 = *(const float2*)(nb + 2 * NV + idx);
        float2 v3 = *(const float2*)(nb + 3 * NV + idx);

        float mxa = fmaxf(fmaxf(v0.x, v1.x), fmaxf(v2.x, v3.x));
        float mxb = fmaxf(fmaxf(v0.y, v1.y), fmaxf(v2.y, v3.y));
        float e1a = __expf(v1.x - mxa), e2a = __expf(v2.x - mxa), e3a = __expf(v3.x - mxa);
        float e1b = __expf(v1.y - mxb), e2b = __expf(v2.y - mxb), e3b = __expf(v3.y - mxb);
        float sa = __expf(v0.x - mxa) + e1a + e2a + e3a;
        float sb = __expf(v0.y - mxb) + e1b + e2b + e3b;
        float ia = __frcp_rn(sa);
        float ib = __frcp_rn(sb);

        const int zp = p % 48;              // voxel z = 2*zp, 2*zp+1
        const int yy = (p / 48) & 127;
        const int xx = p / 6144;
        int2 gg  = *(const int2*)(g + idx);
        int2 gxm = (xx > 0)   ? *(const int2*)(g + idx - SXX) : gg;
        int2 gxp = (xx < 127) ? *(const int2*)(g + idx + SXX) : gg;
        int2 gym = (yy > 0)   ? *(const int2*)(g + idx - ZD)  : gg;
        int2 gyp = (yy < 127) ? *(const int2*)(g + idx + ZD)  : gg;
        int zm0 = (zp > 0)  ? g[idx - 1] : gg.x;
        int zp1 = (zp < 47) ? g[idx + 2] : gg.y;

        float acc = 0.0f;
#pragma unroll
        for (int ci = 1; ci <= 3; ++ci) {
            if ((fbits >> ci) & 1) {
                ushort2 dp = *(const ushort2*)(vb + (size_t)(2 * ci - 2) * NV + idx);
                ushort2 dn = *(const ushort2*)(vb + (size_t)(2 * ci - 1) * NV + idx);
                float ea = (ci == 1) ? e1a : ((ci == 2) ? e2a : e3a);
                float eb = (ci == 1) ? e1b : ((ci == 2) ? e2b : e3b);
                bool bndA = (gg.x == ci) &&
                            (gxm.x != ci || gxp.x != ci || gym.x != ci ||
                             gyp.x != ci || zm0 != ci || gg.y != ci);
                bool bndB = (gg.y == ci) &&
                            (gxm.y != ci || gxp.y != ci || gym.y != ci ||
                             gyp.y != ci || gg.x != ci || zp1 != ci);
                float phiA = bndA ? 0.0f : (sqrtf((float)dn.x) - sqrtf((float)dp.x));
                float phiB = bndB ? 0.0f : (sqrtf((float)dn.y) - sqrtf((float)dp.y));
                acc += (ea * ia) * phiA + (eb * ib) * phiB;
            }
        }
        ls += (double)acc;
    }
    __shared__ double sd[256];
    sd[threadIdx.x] = ls;
    __syncthreads();
    for (int off = 128; off > 0; off >>= 1) {
        if (threadIdx.x < off) sd[threadIdx.x] += sd[threadIdx.x + off];
        __syncthreads();
    }
    if (threadIdx.x == 0) partials[(size_t)b * 1024 + blockIdx.x] = sd[0];
}

// -------------------------------------------------------------- reduce ----
__global__ void k_reduce(const double* __restrict__ partials, int n,
                         float* __restrict__ out) {
    __shared__ double sd[256];
    double ls = 0.0;
    for (int i = threadIdx.x; i < n; i += 256) ls += partials[i];
    sd[threadIdx.x] = ls;
    __syncthreads();
    for (int off = 128; off > 0; off >>= 1) {
        if (threadIdx.x < off) sd[threadIdx.x] += sd[threadIdx.x + off];
        __syncthreads();
    }
    if (threadIdx.x == 0) out[0] = (float)(sd[0] / 9437184.0);
}

// ---------------------------------------------------------------- launch ----
extern "C" void kernel_launch(void* const* d_in, const int* in_sizes, int n_in,
                              void* d_out, int out_size, void* d_ws, size_t ws_size,
                              hipStream_t stream) {
    const float* net = (const float*)d_in[0];
    const int*   gt  = (const int*)d_in[1];
    float* out = (float*)d_out;
    char* ws = (char*)d_ws;

    const size_t xbufB1 = (size_t)6 * NV;                          // u8,  9.4 MB
    const size_t zbufB1 = (size_t)6 * NV * sizeof(unsigned short); // u16, 18.9 MB
    const size_t tail   = (size_t)2048 * sizeof(double) + 64;

    const int nb = (ws_size >= 2 * (xbufB1 + zbufB1) + tail) ? 2 : 1;

    unsigned char*  xbuf = (unsigned char*)ws;
    unsigned short* zbuf = (unsigned short*)(ws + (size_t)nb * xbufB1);
    double* partials = (double*)(ws + (size_t)nb * (xbufB1 + zbufB1));
    int* flags = (int*)((char*)partials + 2048 * sizeof(double));

    hipLaunchKernelGGL(k_zero_flags, dim3(1), dim3(64), 0, stream, flags);

    for (int b0 = 0; b0 < 2; b0 += nb) {
        hipLaunchKernelGGL(k_scan_x, dim3(SXX / 64, nb), dim3(384), 0, stream,
                           gt, xbuf, flags, b0);
        hipLaunchKernelGGL(k_pass_yz, dim3(XD, 6 * nb), dim3(384), 0, stream,
                           xbuf, zbuf);
        hipLaunchKernelGGL(k_accum_batch, dim3(1024, nb), dim3(256), 0, stream,
                           zbuf, gt, net, flags, partials, b0);
    }
    hipLaunchKernelGGL(k_reduce, dim3(1), dim3(256), 0, stream, partials,
                       2048, out);
}